// Round 1
// baseline (1214.503 us; speedup 1.0000x reference)
//
#include <hip/hip_runtime.h>
#include <math.h>

#define N_TOK 4096
#define D_DIM 1024
#define R_REL 92
#define T_TAG 32
#define E_EDGE 8192

// ws int layout:
//   [0..127]    cnt_rel
//   [128..255]  cur_rel (atomic cursors)
//   [256..383]  off_rel (93 used)
//   [384]       n_items
//   [512..1023] items  (r<<16 | chunk), max 348
//   [1024..9215] list_by_rel (edge ids sorted by relation)

__global__ void k_count(const int* __restrict__ rel, int* __restrict__ ws) {
    int e = blockIdx.x * 256 + threadIdx.x;
    if (e < E_EDGE) atomicAdd(&ws[rel[e]], 1);
}

__global__ void k_scan(int* __restrict__ ws) {
    __shared__ int sh[128];
    int t = threadIdx.x;
    int c = (t < R_REL) ? ws[t] : 0;
    // inclusive Hillis-Steele scan of c
    int v = c;
    sh[t] = v; __syncthreads();
    for (int st = 1; st < 128; st <<= 1) {
        int add = (t >= st) ? sh[t - st] : 0;
        __syncthreads();
        v += add; sh[t] = v;
        __syncthreads();
    }
    if (t <= R_REL) ws[256 + t] = v - c;  // exclusive offsets (t=92 -> total)
    // scan of chunk counts
    int ch = (c + 31) >> 5;
    int v2 = ch;
    sh[t] = v2; __syncthreads();
    for (int st = 1; st < 128; st <<= 1) {
        int add = (t >= st) ? sh[t - st] : 0;
        __syncthreads();
        v2 += add; sh[t] = v2;
        __syncthreads();
    }
    int excl = v2 - ch;
    if (t < R_REL) {
        for (int j = 0; j < ch; ++j)
            ws[512 + excl + j] = (t << 16) | j;
    }
    if (t == 127) ws[384] = v2;  // total item count
}

__global__ void k_scatter(const int* __restrict__ rel, int* __restrict__ ws) {
    int e = blockIdx.x * 256 + threadIdx.x;
    if (e >= E_EDGE) return;
    int r = rel[e];
    int pos = ws[256 + r] + atomicAdd(&ws[128 + r], 1);
    ws[1024 + pos] = e;
}

// out_h = x @ W_self + b_self   (128x128 tile, 256 thr, 8x8 per-thread acc)
__global__ __launch_bounds__(256) void k_self(const float* __restrict__ x,
                                              const float* __restrict__ W,
                                              const float* __restrict__ b,
                                              float* __restrict__ out_h) {
    __shared__ float A[16][128];  // A[k][m] (x transposed)
    __shared__ float B[16][128];  // B[k][n]
    int m0 = blockIdx.x * 128, n0 = blockIdx.y * 128;
    int t = threadIdx.x;
    int tr = t >> 4, tc = t & 15;
    float acc[8][8] = {};
    for (int k0 = 0; k0 < D_DIM; k0 += 16) {
        #pragma unroll
        for (int i = 0; i < 2; ++i) {
            int idx = t * 2 + i;            // 0..511 float4 units
            int row = idx >> 2;             // 0..127
            int c4 = (idx & 3) * 4;         // 0,4,8,12
            float4 v = *(const float4*)&x[(size_t)(m0 + row) * D_DIM + k0 + c4];
            A[c4 + 0][row] = v.x; A[c4 + 1][row] = v.y;
            A[c4 + 2][row] = v.z; A[c4 + 3][row] = v.w;
        }
        #pragma unroll
        for (int i = 0; i < 2; ++i) {
            int idx = t * 2 + i;
            int row = idx >> 5;             // 0..15
            int c4 = (idx & 31) * 4;        // 0..124
            *(float4*)&B[row][c4] = *(const float4*)&W[(size_t)(k0 + row) * D_DIM + n0 + c4];
        }
        __syncthreads();
        #pragma unroll
        for (int k = 0; k < 16; ++k) {
            float4 a0 = *(const float4*)&A[k][tr * 8];
            float4 a1 = *(const float4*)&A[k][tr * 8 + 4];
            float4 b0 = *(const float4*)&B[k][tc * 8];
            float4 b1 = *(const float4*)&B[k][tc * 8 + 4];
            float av[8] = {a0.x, a0.y, a0.z, a0.w, a1.x, a1.y, a1.z, a1.w};
            float bv[8] = {b0.x, b0.y, b0.z, b0.w, b1.x, b1.y, b1.z, b1.w};
            #pragma unroll
            for (int i = 0; i < 8; ++i)
                #pragma unroll
                for (int j = 0; j < 8; ++j)
                    acc[i][j] = fmaf(av[i], bv[j], acc[i][j]);
        }
        __syncthreads();
    }
    #pragma unroll
    for (int i = 0; i < 8; ++i) {
        int row = m0 + tr * 8 + i;
        #pragma unroll
        for (int j = 0; j < 8; j += 4) {
            int col = n0 + tc * 8 + j;
            float4 o;
            o.x = acc[i][j + 0] + b[col + 0];
            o.y = acc[i][j + 1] + b[col + 1];
            o.z = acc[i][j + 2] + b[col + 2];
            o.w = acc[i][j + 3] + b[col + 3];
            *(float4*)&out_h[(size_t)row * D_DIM + col] = o;
        }
    }
}

// Grouped dep GEMM: block = (item = 32 edge-rows of relation r) x (512-col half).
// acc += x[tok] @ W_r tile; epilogue adds B_stack[r] and atomicAdds into out_h.
__global__ __launch_bounds__(256) void k_dep(const float* __restrict__ x,
                                             const float* __restrict__ Wst,
                                             const float* __restrict__ Bst,
                                             const int* __restrict__ etok,
                                             const int* __restrict__ ws,
                                             float* __restrict__ out_h) {
    int item_id = blockIdx.x;
    if (item_id >= ws[384]) return;
    int item = ws[512 + item_id];
    int r = item >> 16, chunk = item & 0xFFFF;
    int m0 = chunk * 32;
    int cnt = ws[r];
    int off = ws[256 + r];
    int valid = cnt - m0; if (valid > 32) valid = 32;

    __shared__ int toks[32];
    __shared__ float Wl[16][512];
    __shared__ float xl[32][16];
    int t = threadIdx.x;
    if (t < 32) {
        int tok = 0;
        if (t < valid) tok = etok[ws[1024 + off + m0 + t]];
        toks[t] = tok;
    }
    __syncthreads();

    const float* Wr = Wst + (size_t)r * D_DIM * D_DIM;
    int dbase = blockIdx.y * 512;
    float accA[32] = {}, accB[32] = {};

    for (int k0 = 0; k0 < D_DIM; k0 += 16) {
        #pragma unroll
        for (int i = 0; i < 8; ++i) {
            int idx = i * 256 + t;          // 0..2047 float4 units
            int row = idx >> 7;             // 0..15
            int c4 = (idx & 127) * 4;       // 0..508
            *(float4*)&Wl[row][c4] =
                *(const float4*)&Wr[(size_t)(k0 + row) * D_DIM + dbase + c4];
        }
        if (t < 128) {
            int m = t >> 2, c4 = (t & 3) * 4;
            *(float4*)&xl[m][c4] = *(const float4*)&x[(size_t)toks[m] * D_DIM + k0 + c4];
        }
        __syncthreads();
        #pragma unroll
        for (int kk4 = 0; kk4 < 4; ++kk4) {
            float w0[4], w1[4];
            #pragma unroll
            for (int j = 0; j < 4; ++j) {
                w0[j] = Wl[kk4 * 4 + j][t];
                w1[j] = Wl[kk4 * 4 + j][t + 256];
            }
            #pragma unroll
            for (int m = 0; m < 32; ++m) {
                float4 xv = *(const float4*)&xl[m][kk4 * 4];
                accA[m] = fmaf(xv.x, w0[0], accA[m]);
                accA[m] = fmaf(xv.y, w0[1], accA[m]);
                accA[m] = fmaf(xv.z, w0[2], accA[m]);
                accA[m] = fmaf(xv.w, w0[3], accA[m]);
                accB[m] = fmaf(xv.x, w1[0], accB[m]);
                accB[m] = fmaf(xv.y, w1[1], accB[m]);
                accB[m] = fmaf(xv.z, w1[2], accB[m]);
                accB[m] = fmaf(xv.w, w1[3], accB[m]);
            }
        }
        __syncthreads();
    }

    float biasA = Bst[(size_t)r * D_DIM + dbase + t];
    float biasB = Bst[(size_t)r * D_DIM + dbase + 256 + t];
    #pragma unroll
    for (int m = 0; m < 32; ++m) {
        if (m < valid) {
            size_t base = (size_t)toks[m] * D_DIM + dbase + t;
            atomicAdd(&out_h[base], accA[m] + biasA);
            atomicAdd(&out_h[base + 256], accB[m] + biasB);
        }
    }
}

// relu(h) in place + tag_scores = log_softmax(h @ W_tag + b_tag)
__global__ __launch_bounds__(256) void k_tag(float* __restrict__ out_h,
                                             const float* __restrict__ Wt,
                                             const float* __restrict__ bt,
                                             float* __restrict__ out_tag) {
    __shared__ float hl[8][1024];
    int tok0 = blockIdx.x * 8;
    int t = threadIdx.x;
    #pragma unroll
    for (int i = 0; i < 8; ++i) {
        int idx = i * 256 + t;              // float4 units: 8 rows x 256
        int row = idx >> 8, c4 = (idx & 255) * 4;
        float4 v = *(float4*)&out_h[(size_t)(tok0 + row) * D_DIM + c4];
        v.x = fmaxf(v.x, 0.f); v.y = fmaxf(v.y, 0.f);
        v.z = fmaxf(v.z, 0.f); v.w = fmaxf(v.w, 0.f);
        *(float4*)&out_h[(size_t)(tok0 + row) * D_DIM + c4] = v;
        *(float4*)&hl[row][c4] = v;
    }
    __syncthreads();
    int tl = t >> 5, tt = t & 31;
    float acc = bt[tt];
    for (int k = 0; k < D_DIM; k += 4) {
        acc = fmaf(hl[tl][k + 0], Wt[(size_t)(k + 0) * T_TAG + tt], acc);
        acc = fmaf(hl[tl][k + 1], Wt[(size_t)(k + 1) * T_TAG + tt], acc);
        acc = fmaf(hl[tl][k + 2], Wt[(size_t)(k + 2) * T_TAG + tt], acc);
        acc = fmaf(hl[tl][k + 3], Wt[(size_t)(k + 3) * T_TAG + tt], acc);
    }
    float mx = acc;
    #pragma unroll
    for (int s = 16; s > 0; s >>= 1) mx = fmaxf(mx, __shfl_xor(mx, s, 32));
    float ex = expf(acc - mx);
    float sum = ex;
    #pragma unroll
    for (int s = 16; s > 0; s >>= 1) sum += __shfl_xor(sum, s, 32);
    out_tag[(size_t)(tok0 + tl) * T_TAG + tt] = acc - mx - logf(sum);
}

extern "C" void kernel_launch(void* const* d_in, const int* in_sizes, int n_in,
                              void* d_out, int out_size, void* d_ws, size_t ws_size,
                              hipStream_t stream) {
    const float* x     = (const float*)d_in[0];
    const float* Wself = (const float*)d_in[1];
    const float* bself = (const float*)d_in[2];
    const float* Wst   = (const float*)d_in[3];
    const float* Bst   = (const float*)d_in[4];
    const float* Wtag  = (const float*)d_in[5];
    const float* btag  = (const float*)d_in[6];
    const int*   etok  = (const int*)d_in[7];
    const int*   erel  = (const int*)d_in[8];
    float* out_tag = (float*)d_out;
    float* out_h   = (float*)d_out + (size_t)N_TOK * T_TAG;
    int* ws = (int*)d_ws;

    hipMemsetAsync(d_ws, 0, 2048, stream);  // cnt/cur/off/n_items region
    k_count<<<E_EDGE / 256, 256, 0, stream>>>(erel, ws);
    k_scan<<<1, 128, 0, stream>>>(ws);
    k_scatter<<<E_EDGE / 256, 256, 0, stream>>>(erel, ws);
    k_self<<<dim3(N_TOK / 128, D_DIM / 128), 256, 0, stream>>>(x, Wself, bself, out_h);
    k_dep<<<dim3(512, 2), 256, 0, stream>>>(x, Wst, Bst, etok, ws, out_h);
    k_tag<<<N_TOK / 8, 256, 0, stream>>>(out_h, Wtag, btag, out_tag);
}

// Round 2
// 662.514 us; speedup vs baseline: 1.8332x; 1.8332x over previous
//
#include <hip/hip_runtime.h>
#include <math.h>

#define N_TOK 4096
#define D_DIM 1024
#define R_REL 92
#define T_TAG 32
#define E_EDGE 8192
#define MAX_ITEMS 160

// ws int layout:
//   [0..127]    cnt_rel
//   [128..255]  cur_rel (atomic cursors)
//   [256..383]  off_rel (93 used)
//   [384]       n_items
//   [512..1023] items  (r<<16 | chunk), 128-row chunks, max ~156
//   [1024..9215] list_by_rel (edge ids sorted by relation)

__global__ void k_count(const int* __restrict__ rel, int* __restrict__ ws) {
    int e = blockIdx.x * 256 + threadIdx.x;
    if (e < E_EDGE) atomicAdd(&ws[rel[e]], 1);
}

__global__ void k_scan(int* __restrict__ ws) {
    __shared__ int sh[128];
    int t = threadIdx.x;
    int c = (t < R_REL) ? ws[t] : 0;
    int v = c;
    sh[t] = v; __syncthreads();
    for (int st = 1; st < 128; st <<= 1) {
        int add = (t >= st) ? sh[t - st] : 0;
        __syncthreads();
        v += add; sh[t] = v;
        __syncthreads();
    }
    if (t <= R_REL) ws[256 + t] = v - c;  // exclusive offsets
    // scan of 128-row chunk counts
    int ch = (c + 127) >> 7;
    int v2 = ch;
    sh[t] = v2; __syncthreads();
    for (int st = 1; st < 128; st <<= 1) {
        int add = (t >= st) ? sh[t - st] : 0;
        __syncthreads();
        v2 += add; sh[t] = v2;
        __syncthreads();
    }
    int excl = v2 - ch;
    if (t < R_REL) {
        for (int j = 0; j < ch; ++j)
            ws[512 + excl + j] = (t << 16) | j;
    }
    if (t == 127) ws[384] = v2;
}

__global__ void k_scatter(const int* __restrict__ rel, int* __restrict__ ws) {
    int e = blockIdx.x * 256 + threadIdx.x;
    if (e >= E_EDGE) return;
    int r = rel[e];
    int pos = ws[256 + r] + atomicAdd(&ws[128 + r], 1);
    ws[1024 + pos] = e;
}

// out_h = x @ W_self + b_self   (128x128 tile, 256 thr, 8x8 per-thread acc)
__global__ __launch_bounds__(256) void k_self(const float* __restrict__ x,
                                              const float* __restrict__ W,
                                              const float* __restrict__ b,
                                              float* __restrict__ out_h) {
    __shared__ float A[16][128];  // A[k][m]
    __shared__ float B[16][128];  // B[k][n]
    int m0 = blockIdx.x * 128, n0 = blockIdx.y * 128;
    int t = threadIdx.x;
    int tr = t >> 4, tc = t & 15;
    float acc[8][8] = {};
    for (int k0 = 0; k0 < D_DIM; k0 += 16) {
        #pragma unroll
        for (int i = 0; i < 2; ++i) {
            int idx = t * 2 + i;
            int row = idx >> 2;
            int c4 = (idx & 3) * 4;
            float4 v = *(const float4*)&x[(size_t)(m0 + row) * D_DIM + k0 + c4];
            A[c4 + 0][row] = v.x; A[c4 + 1][row] = v.y;
            A[c4 + 2][row] = v.z; A[c4 + 3][row] = v.w;
        }
        #pragma unroll
        for (int i = 0; i < 2; ++i) {
            int idx = t * 2 + i;
            int row = idx >> 5;
            int c4 = (idx & 31) * 4;
            *(float4*)&B[row][c4] = *(const float4*)&W[(size_t)(k0 + row) * D_DIM + n0 + c4];
        }
        __syncthreads();
        #pragma unroll
        for (int k = 0; k < 16; ++k) {
            float4 a0 = *(const float4*)&A[k][tr * 8];
            float4 a1 = *(const float4*)&A[k][tr * 8 + 4];
            float4 b0 = *(const float4*)&B[k][tc * 8];
            float4 b1 = *(const float4*)&B[k][tc * 8 + 4];
            float av[8] = {a0.x, a0.y, a0.z, a0.w, a1.x, a1.y, a1.z, a1.w};
            float bv[8] = {b0.x, b0.y, b0.z, b0.w, b1.x, b1.y, b1.z, b1.w};
            #pragma unroll
            for (int i = 0; i < 8; ++i)
                #pragma unroll
                for (int j = 0; j < 8; ++j)
                    acc[i][j] = fmaf(av[i], bv[j], acc[i][j]);
        }
        __syncthreads();
    }
    #pragma unroll
    for (int i = 0; i < 8; ++i) {
        int row = m0 + tr * 8 + i;
        #pragma unroll
        for (int j = 0; j < 8; j += 4) {
            int col = n0 + tc * 8 + j;
            float4 o;
            o.x = acc[i][j + 0] + b[col + 0];
            o.y = acc[i][j + 1] + b[col + 1];
            o.z = acc[i][j + 2] + b[col + 2];
            o.w = acc[i][j + 3] + b[col + 3];
            *(float4*)&out_h[(size_t)row * D_DIM + col] = o;
        }
    }
}

// Grouped dep GEMM v2: block = (relation r, 128-row chunk) x 128-col tile.
// Same tiling as k_self; A rows gathered via toks[]; epilogue adds B_stack[r]
// and atomicAdds into out_h for valid rows only.
__global__ __launch_bounds__(256) void k_dep(const float* __restrict__ x,
                                             const float* __restrict__ Wst,
                                             const float* __restrict__ Bst,
                                             const int* __restrict__ etok,
                                             const int* __restrict__ ws,
                                             float* __restrict__ out_h) {
    int item_id = blockIdx.x;
    if (item_id >= ws[384]) return;
    int item = ws[512 + item_id];
    int r = item >> 16, chunk = item & 0xFFFF;
    int m0 = chunk * 128;
    int cnt = ws[r];
    int off = ws[256 + r];
    int valid = cnt - m0; if (valid > 128) valid = 128;

    __shared__ int toks[128];
    __shared__ float A[16][128];
    __shared__ float B[16][128];
    int t = threadIdx.x;
    if (t < 128) {
        int tok = 0;
        if (t < valid) tok = etok[ws[1024 + off + m0 + t]];
        toks[t] = tok;
    }
    __syncthreads();

    const float* Wr = Wst + (size_t)r * D_DIM * D_DIM;
    int n0 = blockIdx.y * 128;
    int tr = t >> 4, tc = t & 15;
    float acc[8][8] = {};
    for (int k0 = 0; k0 < D_DIM; k0 += 16) {
        #pragma unroll
        for (int i = 0; i < 2; ++i) {
            int idx = t * 2 + i;
            int row = idx >> 2;
            int c4 = (idx & 3) * 4;
            float4 v = *(const float4*)&x[(size_t)toks[row] * D_DIM + k0 + c4];
            A[c4 + 0][row] = v.x; A[c4 + 1][row] = v.y;
            A[c4 + 2][row] = v.z; A[c4 + 3][row] = v.w;
        }
        #pragma unroll
        for (int i = 0; i < 2; ++i) {
            int idx = t * 2 + i;
            int row = idx >> 5;
            int c4 = (idx & 31) * 4;
            *(float4*)&B[row][c4] = *(const float4*)&Wr[(size_t)(k0 + row) * D_DIM + n0 + c4];
        }
        __syncthreads();
        #pragma unroll
        for (int k = 0; k < 16; ++k) {
            float4 a0 = *(const float4*)&A[k][tr * 8];
            float4 a1 = *(const float4*)&A[k][tr * 8 + 4];
            float4 b0 = *(const float4*)&B[k][tc * 8];
            float4 b1 = *(const float4*)&B[k][tc * 8 + 4];
            float av[8] = {a0.x, a0.y, a0.z, a0.w, a1.x, a1.y, a1.z, a1.w};
            float bv[8] = {b0.x, b0.y, b0.z, b0.w, b1.x, b1.y, b1.z, b1.w};
            #pragma unroll
            for (int i = 0; i < 8; ++i)
                #pragma unroll
                for (int j = 0; j < 8; ++j)
                    acc[i][j] = fmaf(av[i], bv[j], acc[i][j]);
        }
        __syncthreads();
    }
    #pragma unroll
    for (int i = 0; i < 8; ++i) {
        int ml = tr * 8 + i;
        if (ml < valid) {
            size_t base = (size_t)toks[ml] * D_DIM + n0 + tc * 8;
            const float* br = &Bst[(size_t)r * D_DIM + n0 + tc * 8];
            #pragma unroll
            for (int j = 0; j < 8; ++j)
                atomicAdd(&out_h[base + j], acc[i][j] + br[j]);
        }
    }
}

// relu(h) in place + tag_scores = log_softmax(h @ W_tag + b_tag)
__global__ __launch_bounds__(256) void k_tag(float* __restrict__ out_h,
                                             const float* __restrict__ Wt,
                                             const float* __restrict__ bt,
                                             float* __restrict__ out_tag) {
    __shared__ float hl[8][1024];
    int tok0 = blockIdx.x * 8;
    int t = threadIdx.x;
    #pragma unroll
    for (int i = 0; i < 8; ++i) {
        int idx = i * 256 + t;
        int row = idx >> 8, c4 = (idx & 255) * 4;
        float4 v = *(float4*)&out_h[(size_t)(tok0 + row) * D_DIM + c4];
        v.x = fmaxf(v.x, 0.f); v.y = fmaxf(v.y, 0.f);
        v.z = fmaxf(v.z, 0.f); v.w = fmaxf(v.w, 0.f);
        *(float4*)&out_h[(size_t)(tok0 + row) * D_DIM + c4] = v;
        *(float4*)&hl[row][c4] = v;
    }
    __syncthreads();
    int tl = t >> 5, tt = t & 31;
    float acc = bt[tt];
    for (int k = 0; k < D_DIM; k += 4) {
        acc = fmaf(hl[tl][k + 0], Wt[(size_t)(k + 0) * T_TAG + tt], acc);
        acc = fmaf(hl[tl][k + 1], Wt[(size_t)(k + 1) * T_TAG + tt], acc);
        acc = fmaf(hl[tl][k + 2], Wt[(size_t)(k + 2) * T_TAG + tt], acc);
        acc = fmaf(hl[tl][k + 3], Wt[(size_t)(k + 3) * T_TAG + tt], acc);
    }
    float mx = acc;
    #pragma unroll
    for (int s = 16; s > 0; s >>= 1) mx = fmaxf(mx, __shfl_xor(mx, s, 32));
    float ex = expf(acc - mx);
    float sum = ex;
    #pragma unroll
    for (int s = 16; s > 0; s >>= 1) sum += __shfl_xor(sum, s, 32);
    out_tag[(size_t)(tok0 + tl) * T_TAG + tt] = acc - mx - logf(sum);
}

extern "C" void kernel_launch(void* const* d_in, const int* in_sizes, int n_in,
                              void* d_out, int out_size, void* d_ws, size_t ws_size,
                              hipStream_t stream) {
    const float* x     = (const float*)d_in[0];
    const float* Wself = (const float*)d_in[1];
    const float* bself = (const float*)d_in[2];
    const float* Wst   = (const float*)d_in[3];
    const float* Bst   = (const float*)d_in[4];
    const float* Wtag  = (const float*)d_in[5];
    const float* btag  = (const float*)d_in[6];
    const int*   etok  = (const int*)d_in[7];
    const int*   erel  = (const int*)d_in[8];
    float* out_tag = (float*)d_out;
    float* out_h   = (float*)d_out + (size_t)N_TOK * T_TAG;
    int* ws = (int*)d_ws;

    hipMemsetAsync(d_ws, 0, 2048, stream);
    k_count<<<E_EDGE / 256, 256, 0, stream>>>(erel, ws);
    k_scan<<<1, 128, 0, stream>>>(ws);
    k_scatter<<<E_EDGE / 256, 256, 0, stream>>>(erel, ws);
    k_self<<<dim3(N_TOK / 128, D_DIM / 128), 256, 0, stream>>>(x, Wself, bself, out_h);
    k_dep<<<dim3(MAX_ITEMS, D_DIM / 128), 256, 0, stream>>>(x, Wst, Bst, etok, ws, out_h);
    k_tag<<<N_TOK / 8, 256, 0, stream>>>(out_h, Wtag, btag, out_tag);
}

// Round 3
// 246.848 us; speedup vs baseline: 4.9201x; 2.6839x over previous
//
#include <hip/hip_runtime.h>
#include <math.h>

#define N_TOK 4096
#define D_DIM 1024
#define R_REL 92
#define T_TAG 32
#define E_EDGE 8192
#define MAX_ITEMS 160

typedef short bf16x8 __attribute__((ext_vector_type(8)));
typedef float f32x4 __attribute__((ext_vector_type(4)));

__device__ __forceinline__ unsigned short f2bf(float f) {
    unsigned u = __float_as_uint(f);
    u += 0x7FFFu + ((u >> 16) & 1u);   // round-to-nearest-even
    return (unsigned short)(u >> 16);
}

union Pk8 { uint4 q; unsigned short s[8]; };

// ws int layout:
//   [0..127] cnt_rel | [128..255] cur_rel | [256..383] off_rel | [384] n_items
//   [512..1023] items (r<<16 | chunk) | [1024..9215] edge ids sorted by rel

__global__ void k_count(const int* __restrict__ rel, int* __restrict__ ws) {
    int e = blockIdx.x * 256 + threadIdx.x;
    if (e < E_EDGE) atomicAdd(&ws[rel[e]], 1);
}

__global__ void k_scan(int* __restrict__ ws) {
    __shared__ int sh[128];
    int t = threadIdx.x;
    int c = (t < R_REL) ? ws[t] : 0;
    int v = c;
    sh[t] = v; __syncthreads();
    for (int st = 1; st < 128; st <<= 1) {
        int add = (t >= st) ? sh[t - st] : 0;
        __syncthreads();
        v += add; sh[t] = v;
        __syncthreads();
    }
    if (t <= R_REL) ws[256 + t] = v - c;
    int ch = (c + 127) >> 7;
    int v2 = ch;
    sh[t] = v2; __syncthreads();
    for (int st = 1; st < 128; st <<= 1) {
        int add = (t >= st) ? sh[t - st] : 0;
        __syncthreads();
        v2 += add; sh[t] = v2;
        __syncthreads();
    }
    int excl = v2 - ch;
    if (t < R_REL) {
        for (int j = 0; j < ch; ++j)
            ws[512 + excl + j] = (t << 16) | j;
    }
    if (t == 127) ws[384] = v2;
}

__global__ void k_scatter(const int* __restrict__ rel, int* __restrict__ ws) {
    int e = blockIdx.x * 256 + threadIdx.x;
    if (e >= E_EDGE) return;
    int r = rel[e];
    int pos = ws[256 + r] + atomicAdd(&ws[128 + r], 1);
    ws[1024 + pos] = e;
}

// ---------------- MFMA self GEMM: out_h = x @ W_self + b_self ----------------
// 128x128 tile, BK=64, 4 waves (2x2), per-wave 64x64 = 4x4 frags of 16x16x32.
__global__ __launch_bounds__(256) void k_self(const float* __restrict__ x,
                                              const float* __restrict__ W,
                                              const float* __restrict__ b,
                                              float* __restrict__ out_h) {
    __shared__ unsigned short Al[128 * 64];  // [row][k] bf16, XOR-swizzled
    __shared__ unsigned short Bl[128 * 64];  // [n][k]   bf16, XOR-swizzled
    char* Alb = (char*)Al;
    char* Blb = (char*)Bl;
    int m0 = blockIdx.x * 128, n0 = blockIdx.y * 128;
    int t = threadIdx.x;
    int w = t >> 6, l = t & 63;
    int lr = l & 15, lg = l >> 4;
    int wm = (w >> 1) * 64, wn = (w & 1) * 64;

    // staging maps
    int arow = t >> 1, ahalf = t & 1;              // A: 2 thr/row, 32 f32 each
    int bn = (w & 1) * 64 + l;                     // B: col-slice per lane
    int bkb = (w >> 1) * 32;

    f32x4 acc[4][4] = {};
    for (int k0 = 0; k0 < D_DIM; k0 += 64) {
        __syncthreads();
        const float* xr = x + (size_t)(m0 + arow) * D_DIM + k0 + ahalf * 32;
        #pragma unroll
        for (int s = 0; s < 4; ++s) {
            float4 v0 = *(const float4*)(xr + s * 8);
            float4 v1 = *(const float4*)(xr + s * 8 + 4);
            Pk8 u;
            u.s[0] = f2bf(v0.x); u.s[1] = f2bf(v0.y);
            u.s[2] = f2bf(v0.z); u.s[3] = f2bf(v0.w);
            u.s[4] = f2bf(v1.x); u.s[5] = f2bf(v1.y);
            u.s[6] = f2bf(v1.z); u.s[7] = f2bf(v1.w);
            int off = arow * 128 + ((ahalf * 64 + s * 16) ^ ((arow & 7) << 4));
            *(uint4*)(Alb + off) = u.q;
        }
        const float* wp = W + (size_t)(k0 + bkb) * D_DIM + n0 + bn;
        #pragma unroll
        for (int s = 0; s < 4; ++s) {
            Pk8 u;
            #pragma unroll
            for (int i = 0; i < 8; ++i)
                u.s[i] = f2bf(wp[(size_t)(s * 8 + i) * D_DIM]);
            int off = bn * 128 + ((bkb * 2 + s * 16) ^ ((bn & 7) << 4));
            *(uint4*)(Blb + off) = u.q;
        }
        __syncthreads();
        #pragma unroll
        for (int kk = 0; kk < 2; ++kk) {
            int koff = kk * 64 + lg * 16;
            bf16x8 af[4], bf[4];
            #pragma unroll
            for (int mi = 0; mi < 4; ++mi)
                af[mi] = *(const bf16x8*)(Alb + (wm + mi * 16 + lr) * 128 +
                                          (koff ^ ((lr & 7) << 4)));
            #pragma unroll
            for (int ni = 0; ni < 4; ++ni)
                bf[ni] = *(const bf16x8*)(Blb + (wn + ni * 16 + lr) * 128 +
                                          (koff ^ ((lr & 7) << 4)));
            #pragma unroll
            for (int mi = 0; mi < 4; ++mi)
                #pragma unroll
                for (int ni = 0; ni < 4; ++ni)
                    acc[mi][ni] = __builtin_amdgcn_mfma_f32_16x16x32_bf16(
                        af[mi], bf[ni], acc[mi][ni], 0, 0, 0);
        }
    }
    float bb[4];
    #pragma unroll
    for (int ni = 0; ni < 4; ++ni) bb[ni] = b[n0 + wn + ni * 16 + lr];
    #pragma unroll
    for (int mi = 0; mi < 4; ++mi)
        #pragma unroll
        for (int j = 0; j < 4; ++j) {
            int row = m0 + wm + mi * 16 + lg * 4 + j;
            float* dst = out_h + (size_t)row * D_DIM + n0 + wn + lr;
            #pragma unroll
            for (int ni = 0; ni < 4; ++ni)
                dst[ni * 16] = acc[mi][ni][j] + bb[ni];
        }
}

// ---------------- MFMA grouped dep GEMM ----------------
// block = (relation r, 128-row chunk) x 128-col tile; gathered A rows;
// epilogue adds B_stack[r] and atomicAdds into out_h.
__global__ __launch_bounds__(256) void k_dep(const float* __restrict__ x,
                                             const float* __restrict__ Wst,
                                             const float* __restrict__ Bst,
                                             const int* __restrict__ etok,
                                             const int* __restrict__ ws,
                                             float* __restrict__ out_h) {
    int item_id = blockIdx.x;
    if (item_id >= ws[384]) return;
    int item = ws[512 + item_id];
    int r = item >> 16, chunk = item & 0xFFFF;
    int m0 = chunk * 128;
    int cnt = ws[r];
    int off0 = ws[256 + r];
    int valid = cnt - m0; if (valid > 128) valid = 128;

    __shared__ unsigned short Al[128 * 64];
    __shared__ unsigned short Bl[128 * 64];
    __shared__ int toks[128];
    char* Alb = (char*)Al;
    char* Blb = (char*)Bl;
    int t = threadIdx.x;
    if (t < 128) {
        int tok = 0;
        if (t < valid) tok = etok[ws[1024 + off0 + m0 + t]];
        toks[t] = tok;
    }
    __syncthreads();

    const float* Wr = Wst + (size_t)r * D_DIM * D_DIM;
    int gn0 = blockIdx.y * 128;
    int w = t >> 6, l = t & 63;
    int lr = l & 15, lg = l >> 4;
    int wm = (w >> 1) * 64, wn = (w & 1) * 64;
    int arow = t >> 1, ahalf = t & 1;
    int bn = (w & 1) * 64 + l;
    int bkb = (w >> 1) * 32;
    int atok = toks[arow];

    f32x4 acc[4][4] = {};
    for (int k0 = 0; k0 < D_DIM; k0 += 64) {
        __syncthreads();
        const float* xr = x + (size_t)atok * D_DIM + k0 + ahalf * 32;
        #pragma unroll
        for (int s = 0; s < 4; ++s) {
            float4 v0 = *(const float4*)(xr + s * 8);
            float4 v1 = *(const float4*)(xr + s * 8 + 4);
            Pk8 u;
            u.s[0] = f2bf(v0.x); u.s[1] = f2bf(v0.y);
            u.s[2] = f2bf(v0.z); u.s[3] = f2bf(v0.w);
            u.s[4] = f2bf(v1.x); u.s[5] = f2bf(v1.y);
            u.s[6] = f2bf(v1.z); u.s[7] = f2bf(v1.w);
            int off = arow * 128 + ((ahalf * 64 + s * 16) ^ ((arow & 7) << 4));
            *(uint4*)(Alb + off) = u.q;
        }
        const float* wp = Wr + (size_t)(k0 + bkb) * D_DIM + gn0 + bn;
        #pragma unroll
        for (int s = 0; s < 4; ++s) {
            Pk8 u;
            #pragma unroll
            for (int i = 0; i < 8; ++i)
                u.s[i] = f2bf(wp[(size_t)(s * 8 + i) * D_DIM]);
            int off = bn * 128 + ((bkb * 2 + s * 16) ^ ((bn & 7) << 4));
            *(uint4*)(Blb + off) = u.q;
        }
        __syncthreads();
        #pragma unroll
        for (int kk = 0; kk < 2; ++kk) {
            int koff = kk * 64 + lg * 16;
            bf16x8 af[4], bf[4];
            #pragma unroll
            for (int mi = 0; mi < 4; ++mi)
                af[mi] = *(const bf16x8*)(Alb + (wm + mi * 16 + lr) * 128 +
                                          (koff ^ ((lr & 7) << 4)));
            #pragma unroll
            for (int ni = 0; ni < 4; ++ni)
                bf[ni] = *(const bf16x8*)(Blb + (wn + ni * 16 + lr) * 128 +
                                          (koff ^ ((lr & 7) << 4)));
            #pragma unroll
            for (int mi = 0; mi < 4; ++mi)
                #pragma unroll
                for (int ni = 0; ni < 4; ++ni)
                    acc[mi][ni] = __builtin_amdgcn_mfma_f32_16x16x32_bf16(
                        af[mi], bf[ni], acc[mi][ni], 0, 0, 0);
        }
    }
    float bb[4];
    #pragma unroll
    for (int ni = 0; ni < 4; ++ni)
        bb[ni] = Bst[(size_t)r * D_DIM + gn0 + wn + ni * 16 + lr];
    #pragma unroll
    for (int mi = 0; mi < 4; ++mi)
        #pragma unroll
        for (int j = 0; j < 4; ++j) {
            int rl = wm + mi * 16 + lg * 4 + j;
            if (rl < valid) {
                float* dst = out_h + (size_t)toks[rl] * D_DIM + gn0 + wn + lr;
                #pragma unroll
                for (int ni = 0; ni < 4; ++ni)
                    atomicAdd(dst + ni * 16, acc[mi][ni][j] + bb[ni]);
            }
        }
}

// relu(h) in place + tag_scores = log_softmax(h @ W_tag + b_tag)
__global__ __launch_bounds__(256) void k_tag(float* __restrict__ out_h,
                                             const float* __restrict__ Wt,
                                             const float* __restrict__ bt,
                                             float* __restrict__ out_tag) {
    __shared__ float hl[8][1024];
    int tok0 = blockIdx.x * 8;
    int t = threadIdx.x;
    #pragma unroll
    for (int i = 0; i < 8; ++i) {
        int idx = i * 256 + t;
        int row = idx >> 8, c4 = (idx & 255) * 4;
        float4 v = *(float4*)&out_h[(size_t)(tok0 + row) * D_DIM + c4];
        v.x = fmaxf(v.x, 0.f); v.y = fmaxf(v.y, 0.f);
        v.z = fmaxf(v.z, 0.f); v.w = fmaxf(v.w, 0.f);
        *(float4*)&out_h[(size_t)(tok0 + row) * D_DIM + c4] = v;
        *(float4*)&hl[row][c4] = v;
    }
    __syncthreads();
    int tl = t >> 5, tt = t & 31;
    float acc = bt[tt];
    for (int k = 0; k < D_DIM; k += 4) {
        acc = fmaf(hl[tl][k + 0], Wt[(size_t)(k + 0) * T_TAG + tt], acc);
        acc = fmaf(hl[tl][k + 1], Wt[(size_t)(k + 1) * T_TAG + tt], acc);
        acc = fmaf(hl[tl][k + 2], Wt[(size_t)(k + 2) * T_TAG + tt], acc);
        acc = fmaf(hl[tl][k + 3], Wt[(size_t)(k + 3) * T_TAG + tt], acc);
    }
    float mx = acc;
    #pragma unroll
    for (int s = 16; s > 0; s >>= 1) mx = fmaxf(mx, __shfl_xor(mx, s, 32));
    float ex = expf(acc - mx);
    float sum = ex;
    #pragma unroll
    for (int s = 16; s > 0; s >>= 1) sum += __shfl_xor(sum, s, 32);
    out_tag[(size_t)(tok0 + tl) * T_TAG + tt] = acc - mx - logf(sum);
}

extern "C" void kernel_launch(void* const* d_in, const int* in_sizes, int n_in,
                              void* d_out, int out_size, void* d_ws, size_t ws_size,
                              hipStream_t stream) {
    const float* x     = (const float*)d_in[0];
    const float* Wself = (const float*)d_in[1];
    const float* bself = (const float*)d_in[2];
    const float* Wst   = (const float*)d_in[3];
    const float* Bst   = (const float*)d_in[4];
    const float* Wtag  = (const float*)d_in[5];
    const float* btag  = (const float*)d_in[6];
    const int*   etok  = (const int*)d_in[7];
    const int*   erel  = (const int*)d_in[8];
    float* out_tag = (float*)d_out;
    float* out_h   = (float*)d_out + (size_t)N_TOK * T_TAG;
    int* ws = (int*)d_ws;

    hipMemsetAsync(d_ws, 0, 2048, stream);
    k_count<<<E_EDGE / 256, 256, 0, stream>>>(erel, ws);
    k_scan<<<1, 128, 0, stream>>>(ws);
    k_scatter<<<E_EDGE / 256, 256, 0, stream>>>(erel, ws);
    k_self<<<dim3(N_TOK / 128, D_DIM / 128), 256, 0, stream>>>(x, Wself, bself, out_h);
    k_dep<<<dim3(MAX_ITEMS, D_DIM / 128), 256, 0, stream>>>(x, Wst, Bst, etok, ws, out_h);
    k_tag<<<N_TOK / 8, 256, 0, stream>>>(out_h, Wtag, btag, out_tag);
}

// Round 4
// 199.339 us; speedup vs baseline: 6.0926x; 1.2383x over previous
//
#include <hip/hip_runtime.h>
#include <hip/hip_bf16.h>
#include <math.h>

#define N_TOK 4096
#define D_DIM 1024
#define R_REL 92
#define T_TAG 32
#define E_EDGE 8192
#define SELF_R 127
#define GRID_ITEMS 192   // 32 self chunks + up to 160 dep chunks

typedef short bf16x8 __attribute__((ext_vector_type(8)));
typedef float f32x4 __attribute__((ext_vector_type(4)));

union Pk8 { uint4 q; unsigned short s[8]; };

__device__ __forceinline__ unsigned short f2bf(float f) {
    union { __hip_bfloat16 b; unsigned short u; } c;
    c.b = __float2bfloat16(f);
    return c.u;
}

// ws int layout:
//   [0..127] cnt_rel | [256..383] off_rel | [384] n_items
//   [512..1023] items (r<<16 | chunk); items[0..31] are self chunks (r=SELF_R)
//   [1024..9215] edge ids sorted by relation

// One-block setup: count, scan, build items, scatter-sort edges by relation.
__global__ __launch_bounds__(1024) void k_setup(const int* __restrict__ rel,
                                                int* __restrict__ ws) {
    __shared__ int cnt[128], offL[128], cur[128], sh[128];
    int t = threadIdx.x;
    if (t < 128) cnt[t] = 0;
    __syncthreads();
    #pragma unroll
    for (int i = 0; i < E_EDGE / 1024; ++i)
        atomicAdd(&cnt[rel[i * 1024 + t]], 1);
    __syncthreads();
    int c = (t < 128) ? cnt[t] : 0;
    // scan 1: edge-count offsets
    int v = c;
    if (t < 128) sh[t] = v;
    __syncthreads();
    for (int st = 1; st < 128; st <<= 1) {
        int add = (t >= st && t < 128) ? sh[t - st] : 0;
        __syncthreads();
        if (t < 128) { v += add; sh[t] = v; }
        __syncthreads();
    }
    if (t < 128) { offL[t] = v - c; ws[256 + t] = v - c; ws[t] = c; cur[t] = 0; }
    // scan 2: chunk-count offsets
    int ch = (t < R_REL) ? ((c + 127) >> 7) : 0;
    int v2 = ch;
    if (t < 128) sh[t] = v2;
    __syncthreads();
    for (int st = 1; st < 128; st <<= 1) {
        int add = (t >= st && t < 128) ? sh[t - st] : 0;
        __syncthreads();
        if (t < 128) { v2 += add; sh[t] = v2; }
        __syncthreads();
    }
    if (t < 32) ws[512 + t] = (SELF_R << 16) | t;          // self items first
    if (t < R_REL) {
        int excl = v2 - ch;
        for (int j = 0; j < ch; ++j)
            ws[512 + 32 + excl + j] = (t << 16) | j;
    }
    if (t == 127) ws[384] = 32 + v2;                        // total items
    __syncthreads();
    #pragma unroll
    for (int i = 0; i < E_EDGE / 1024; ++i) {
        int e = i * 1024 + t;
        int r = rel[e];
        int pos = offL[r] + atomicAdd(&cur[r], 1);
        ws[1024 + pos] = e;
    }
}

// Fused grouped GEMM: item = (relation | SELF, 128-row chunk) x 128-col tile.
// h (pre-zeroed) += x[rows] @ W + bias via atomicAdd. 128x128xBK=64 MFMA tile,
// 4 waves (2x2), per-wave 64x64 = 4x4 frags of 16x16x32_bf16, XOR-swizzled LDS.
__global__ __launch_bounds__(256) void k_fused(const float* __restrict__ x,
                                               const float* __restrict__ Wself,
                                               const float* __restrict__ bself,
                                               const float* __restrict__ Wst,
                                               const float* __restrict__ Bst,
                                               const int* __restrict__ etok,
                                               const int* __restrict__ ws,
                                               float* __restrict__ out_h) {
    if ((int)blockIdx.x >= ws[384]) return;
    int item = ws[512 + blockIdx.x];
    int r = item >> 16, chunk = item & 0xFFFF;
    int m0 = chunk * 128;
    int valid;
    const float* Wbase;
    const float* bias;
    bool is_self = (r == SELF_R);
    int off0 = 0;
    if (is_self) {
        valid = 128;
        Wbase = Wself;
        bias = bself;
    } else {
        int cnt = ws[r];
        off0 = ws[256 + r];
        valid = cnt - m0; if (valid > 128) valid = 128;
        Wbase = Wst + (size_t)r * D_DIM * D_DIM;
        bias = Bst + (size_t)r * D_DIM;
    }

    __shared__ unsigned short Al[128 * 64];
    __shared__ unsigned short Bl[128 * 64];
    __shared__ int toks[128];
    char* Alb = (char*)Al;
    char* Blb = (char*)Bl;
    int t = threadIdx.x;
    if (t < 128) {
        int tok;
        if (is_self) tok = m0 + t;
        else tok = (t < valid) ? etok[ws[1024 + off0 + m0 + t]] : 0;
        toks[t] = tok;
    }
    __syncthreads();

    int gn0 = blockIdx.y * 128;
    int w = t >> 6, l = t & 63;
    int lr = l & 15, lg = l >> 4;
    int wm = (w >> 1) * 64, wn = (w & 1) * 64;
    int arow = t >> 1, ahalf = t & 1;
    int bn = (w & 1) * 64 + l;
    int bkb = (w >> 1) * 32;
    int atok = toks[arow];

    f32x4 acc[4][4] = {};
    for (int k0 = 0; k0 < D_DIM; k0 += 64) {
        __syncthreads();
        const float* xr = x + (size_t)atok * D_DIM + k0 + ahalf * 32;
        #pragma unroll
        for (int s = 0; s < 4; ++s) {
            float4 v0 = *(const float4*)(xr + s * 8);
            float4 v1 = *(const float4*)(xr + s * 8 + 4);
            Pk8 u;
            u.s[0] = f2bf(v0.x); u.s[1] = f2bf(v0.y);
            u.s[2] = f2bf(v0.z); u.s[3] = f2bf(v0.w);
            u.s[4] = f2bf(v1.x); u.s[5] = f2bf(v1.y);
            u.s[6] = f2bf(v1.z); u.s[7] = f2bf(v1.w);
            int off = arow * 128 + ((ahalf * 64 + s * 16) ^ ((arow & 7) << 4));
            *(uint4*)(Alb + off) = u.q;
        }
        const float* wp = Wbase + (size_t)(k0 + bkb) * D_DIM + gn0 + bn;
        #pragma unroll
        for (int s = 0; s < 4; ++s) {
            Pk8 u;
            #pragma unroll
            for (int i = 0; i < 8; ++i)
                u.s[i] = f2bf(wp[(size_t)(s * 8 + i) * D_DIM]);
            int off = bn * 128 + ((bkb * 2 + s * 16) ^ ((bn & 7) << 4));
            *(uint4*)(Blb + off) = u.q;
        }
        __syncthreads();
        #pragma unroll
        for (int kk = 0; kk < 2; ++kk) {
            int koff = kk * 64 + lg * 16;
            bf16x8 af[4], bf[4];
            #pragma unroll
            for (int mi = 0; mi < 4; ++mi)
                af[mi] = *(const bf16x8*)(Alb + (wm + mi * 16 + lr) * 128 +
                                          (koff ^ ((lr & 7) << 4)));
            #pragma unroll
            for (int ni = 0; ni < 4; ++ni)
                bf[ni] = *(const bf16x8*)(Blb + (wn + ni * 16 + lr) * 128 +
                                          (koff ^ ((lr & 7) << 4)));
            #pragma unroll
            for (int mi = 0; mi < 4; ++mi)
                #pragma unroll
                for (int ni = 0; ni < 4; ++ni)
                    acc[mi][ni] = __builtin_amdgcn_mfma_f32_16x16x32_bf16(
                        af[mi], bf[ni], acc[mi][ni], 0, 0, 0);
        }
    }
    float bb[4];
    #pragma unroll
    for (int ni = 0; ni < 4; ++ni) bb[ni] = bias[gn0 + wn + ni * 16 + lr];
    #pragma unroll
    for (int mi = 0; mi < 4; ++mi)
        #pragma unroll
        for (int j = 0; j < 4; ++j) {
            int rl = wm + mi * 16 + lg * 4 + j;
            if (rl < valid) {
                float* dst = out_h + (size_t)toks[rl] * D_DIM + gn0 + wn + lr;
                #pragma unroll
                for (int ni = 0; ni < 4; ++ni)
                    atomicAdd(dst + ni * 16, acc[mi][ni][j] + bb[ni]);
            }
        }
}

// relu(h) in place + tag_scores = log_softmax(h @ W_tag + b_tag)
__global__ __launch_bounds__(256) void k_tag(float* __restrict__ out_h,
                                             const float* __restrict__ Wt,
                                             const float* __restrict__ bt,
                                             float* __restrict__ out_tag) {
    __shared__ float hl[8][1024];
    int tok0 = blockIdx.x * 8;
    int t = threadIdx.x;
    #pragma unroll
    for (int i = 0; i < 8; ++i) {
        int idx = i * 256 + t;
        int row = idx >> 8, c4 = (idx & 255) * 4;
        float4 v = *(float4*)&out_h[(size_t)(tok0 + row) * D_DIM + c4];
        v.x = fmaxf(v.x, 0.f); v.y = fmaxf(v.y, 0.f);
        v.z = fmaxf(v.z, 0.f); v.w = fmaxf(v.w, 0.f);
        *(float4*)&out_h[(size_t)(tok0 + row) * D_DIM + c4] = v;
        *(float4*)&hl[row][c4] = v;
    }
    __syncthreads();
    int tl = t >> 5, tt = t & 31;
    float acc = bt[tt];
    for (int k = 0; k < D_DIM; k += 4) {
        acc = fmaf(hl[tl][k + 0], Wt[(size_t)(k + 0) * T_TAG + tt], acc);
        acc = fmaf(hl[tl][k + 1], Wt[(size_t)(k + 1) * T_TAG + tt], acc);
        acc = fmaf(hl[tl][k + 2], Wt[(size_t)(k + 2) * T_TAG + tt], acc);
        acc = fmaf(hl[tl][k + 3], Wt[(size_t)(k + 3) * T_TAG + tt], acc);
    }
    float mx = acc;
    #pragma unroll
    for (int s = 16; s > 0; s >>= 1) mx = fmaxf(mx, __shfl_xor(mx, s, 32));
    float ex = expf(acc - mx);
    float sum = ex;
    #pragma unroll
    for (int s = 16; s > 0; s >>= 1) sum += __shfl_xor(sum, s, 32);
    out_tag[(size_t)(tok0 + tl) * T_TAG + tt] = acc - mx - logf(sum);
}

extern "C" void kernel_launch(void* const* d_in, const int* in_sizes, int n_in,
                              void* d_out, int out_size, void* d_ws, size_t ws_size,
                              hipStream_t stream) {
    const float* x     = (const float*)d_in[0];
    const float* Wself = (const float*)d_in[1];
    const float* bself = (const float*)d_in[2];
    const float* Wst   = (const float*)d_in[3];
    const float* Bst   = (const float*)d_in[4];
    const float* Wtag  = (const float*)d_in[5];
    const float* btag  = (const float*)d_in[6];
    const int*   etok  = (const int*)d_in[7];
    const int*   erel  = (const int*)d_in[8];
    float* out_tag = (float*)d_out;
    float* out_h   = (float*)d_out + (size_t)N_TOK * T_TAG;
    int* ws = (int*)d_ws;

    hipMemsetAsync(out_h, 0, (size_t)N_TOK * D_DIM * sizeof(float), stream);
    k_setup<<<1, 1024, 0, stream>>>(erel, ws);
    k_fused<<<dim3(GRID_ITEMS, D_DIM / 128), 256, 0, stream>>>(
        x, Wself, bself, Wst, Bst, etok, ws, out_h);
    k_tag<<<N_TOK / 8, 256, 0, stream>>>(out_h, Wtag, btag, out_tag);
}

// Round 5
// 165.493 us; speedup vs baseline: 7.3387x; 1.2045x over previous
//
#include <hip/hip_runtime.h>
#include <hip/hip_bf16.h>
#include <math.h>

#define N_TOK 4096
#define D_DIM 1024
#define R_REL 92
#define T_TAG 32
#define E_EDGE 8192
#define SELF_R 127
#define GRID_ITEMS 192   // 32 self chunks + up to 160 dep chunks

typedef short bf16x8 __attribute__((ext_vector_type(8)));
typedef float f32x4 __attribute__((ext_vector_type(4)));

union Pk8 { uint4 q; unsigned short s[8]; };
union Pk4 { uint2 d; unsigned short s[4]; };

__device__ __forceinline__ unsigned short f2bf(float f) {
    union { __hip_bfloat16 b; unsigned short u; } c;
    c.b = __float2bfloat16(f);
    return c.u;
}

// ws int layout:
//   [0..127] cnt_rel | [256..383] off_rel | [384] n_items
//   [512..1023] items (r<<16 | chunk); items[0..31] are self chunks (r=SELF_R)
//   [1024..9215] edge ids sorted by relation

__global__ __launch_bounds__(1024) void k_setup(const int* __restrict__ rel,
                                                int* __restrict__ ws) {
    __shared__ int cnt[128], offL[128], cur[128], sh[128];
    int t = threadIdx.x;
    if (t < 128) cnt[t] = 0;
    __syncthreads();
    #pragma unroll
    for (int i = 0; i < E_EDGE / 1024; ++i)
        atomicAdd(&cnt[rel[i * 1024 + t]], 1);
    __syncthreads();
    int c = (t < 128) ? cnt[t] : 0;
    int v = c;
    if (t < 128) sh[t] = v;
    __syncthreads();
    for (int st = 1; st < 128; st <<= 1) {
        int add = (t >= st && t < 128) ? sh[t - st] : 0;
        __syncthreads();
        if (t < 128) { v += add; sh[t] = v; }
        __syncthreads();
    }
    if (t < 128) { offL[t] = v - c; ws[256 + t] = v - c; ws[t] = c; cur[t] = 0; }
    int ch = (t < R_REL) ? ((c + 127) >> 7) : 0;
    int v2 = ch;
    if (t < 128) sh[t] = v2;
    __syncthreads();
    for (int st = 1; st < 128; st <<= 1) {
        int add = (t >= st && t < 128) ? sh[t - st] : 0;
        __syncthreads();
        if (t < 128) { v2 += add; sh[t] = v2; }
        __syncthreads();
    }
    if (t < 32) ws[512 + t] = (SELF_R << 16) | t;
    if (t < R_REL) {
        int excl = v2 - ch;
        for (int j = 0; j < ch; ++j)
            ws[512 + 32 + excl + j] = (t << 16) | j;
    }
    if (t == 127) ws[384] = 32 + v2;
    __syncthreads();
    #pragma unroll
    for (int i = 0; i < E_EDGE / 1024; ++i) {
        int e = i * 1024 + t;
        int r = rel[e];
        int pos = offL[r] + atomicAdd(&cur[r], 1);
        ws[1024 + pos] = e;
    }
}

// Fused grouped GEMM, T14 pipelined: issue loads(t+1) -> MFMA(t) -> barrier ->
// convert+ds_write(t+1) -> barrier. 128x128xBK=64, 4 waves, 16x16x32_bf16.
__global__ __launch_bounds__(256, 2) void k_fused(const float* __restrict__ x,
                                                  const float* __restrict__ Wself,
                                                  const float* __restrict__ bself,
                                                  const float* __restrict__ Wst,
                                                  const float* __restrict__ Bst,
                                                  const int* __restrict__ etok,
                                                  const int* __restrict__ ws,
                                                  float* __restrict__ out_h) {
    if ((int)blockIdx.x >= ws[384]) return;
    int item = ws[512 + blockIdx.x];
    int r = item >> 16, chunk = item & 0xFFFF;
    int m0 = chunk * 128;
    int valid;
    const float* Wbase;
    const float* bias;
    bool is_self = (r == SELF_R);
    int off0 = 0;
    if (is_self) {
        valid = 128;
        Wbase = Wself;
        bias = bself;
    } else {
        int cnt = ws[r];
        off0 = ws[256 + r];
        valid = cnt - m0; if (valid > 128) valid = 128;
        Wbase = Wst + (size_t)r * D_DIM * D_DIM;
        bias = Bst + (size_t)r * D_DIM;
    }

    __shared__ unsigned short Al[128 * 64];
    __shared__ unsigned short Bl[128 * 64];
    __shared__ int toks[128];
    char* Alb = (char*)Al;
    char* Blb = (char*)Bl;
    int t = threadIdx.x;
    if (t < 128) {
        int tok;
        if (is_self) tok = m0 + t;
        else tok = (t < valid) ? etok[ws[1024 + off0 + m0 + t]] : 0;
        toks[t] = tok;
    }
    __syncthreads();

    int gn0 = blockIdx.y * 128;
    int w = t >> 6, l = t & 63;
    int lr = l & 15, lg = l >> 4;
    int wm = (w >> 1) * 64, wn = (w & 1) * 64;
    // A-stage: 16 threads/row (coalesced 256B rows); 8 row-sets
    int ar = t >> 4, ac = t & 15;
    int tok_s[8];
    #pragma unroll
    for (int s = 0; s < 8; ++s) tok_s[s] = toks[s * 16 + ar];
    // B-stage: column gather
    int bn = (w & 1) * 64 + l;
    int bkb = (w >> 1) * 32;
    const float* wcol = Wbase + gn0 + bn;

    float4 pa[8];
    float pb[32];

    // prologue: load + stage tile 0
    #pragma unroll
    for (int s = 0; s < 8; ++s)
        pa[s] = *(const float4*)(x + (size_t)tok_s[s] * D_DIM + ac * 4);
    #pragma unroll
    for (int s = 0; s < 4; ++s)
        #pragma unroll
        for (int i = 0; i < 8; ++i)
            pb[s * 8 + i] = wcol[(size_t)(bkb + s * 8 + i) * D_DIM];
    #pragma unroll
    for (int s = 0; s < 8; ++s) {
        int row = s * 16 + ar;
        Pk4 u;
        u.s[0] = f2bf(pa[s].x); u.s[1] = f2bf(pa[s].y);
        u.s[2] = f2bf(pa[s].z); u.s[3] = f2bf(pa[s].w);
        *(uint2*)(Alb + row * 128 + ((ac * 8) ^ ((row & 7) << 4))) = u.d;
    }
    #pragma unroll
    for (int s = 0; s < 4; ++s) {
        Pk8 u;
        #pragma unroll
        for (int i = 0; i < 8; ++i) u.s[i] = f2bf(pb[s * 8 + i]);
        *(uint4*)(Blb + bn * 128 + ((bkb * 2 + s * 16) ^ ((bn & 7) << 4))) = u.q;
    }
    __syncthreads();

    f32x4 acc[4][4] = {};
    for (int k0 = 0; k0 < D_DIM; k0 += 64) {
        bool pf = (k0 + 64 < D_DIM);
        if (pf) {                       // issue next-tile loads (stay in flight)
            int kn = k0 + 64;
            #pragma unroll
            for (int s = 0; s < 8; ++s)
                pa[s] = *(const float4*)(x + (size_t)tok_s[s] * D_DIM + kn + ac * 4);
            #pragma unroll
            for (int s = 0; s < 4; ++s)
                #pragma unroll
                for (int i = 0; i < 8; ++i)
                    pb[s * 8 + i] = wcol[(size_t)(kn + bkb + s * 8 + i) * D_DIM];
        }
        #pragma unroll
        for (int kk = 0; kk < 2; ++kk) {
            int koff = kk * 64 + lg * 16;
            bf16x8 af[4], bfr[4];
            #pragma unroll
            for (int mi = 0; mi < 4; ++mi)
                af[mi] = *(const bf16x8*)(Alb + (wm + mi * 16 + lr) * 128 +
                                          (koff ^ ((lr & 7) << 4)));
            #pragma unroll
            for (int ni = 0; ni < 4; ++ni)
                bfr[ni] = *(const bf16x8*)(Blb + (wn + ni * 16 + lr) * 128 +
                                           (koff ^ ((lr & 7) << 4)));
            #pragma unroll
            for (int mi = 0; mi < 4; ++mi)
                #pragma unroll
                for (int ni = 0; ni < 4; ++ni)
                    acc[mi][ni] = __builtin_amdgcn_mfma_f32_16x16x32_bf16(
                        af[mi], bfr[ni], acc[mi][ni], 0, 0, 0);
        }
        __syncthreads();                 // all waves done reading LDS(t)
        if (pf) {                        // convert+write tile t+1
            #pragma unroll
            for (int s = 0; s < 8; ++s) {
                int row = s * 16 + ar;
                Pk4 u;
                u.s[0] = f2bf(pa[s].x); u.s[1] = f2bf(pa[s].y);
                u.s[2] = f2bf(pa[s].z); u.s[3] = f2bf(pa[s].w);
                *(uint2*)(Alb + row * 128 + ((ac * 8) ^ ((row & 7) << 4))) = u.d;
            }
            #pragma unroll
            for (int s = 0; s < 4; ++s) {
                Pk8 u;
                #pragma unroll
                for (int i = 0; i < 8; ++i) u.s[i] = f2bf(pb[s * 8 + i]);
                *(uint4*)(Blb + bn * 128 + ((bkb * 2 + s * 16) ^ ((bn & 7) << 4))) = u.q;
            }
            __syncthreads();             // writes visible for next compute
        }
    }
    float bb[4];
    #pragma unroll
    for (int ni = 0; ni < 4; ++ni) bb[ni] = bias[gn0 + wn + ni * 16 + lr];
    #pragma unroll
    for (int mi = 0; mi < 4; ++mi)
        #pragma unroll
        for (int j = 0; j < 4; ++j) {
            int rl = wm + mi * 16 + lg * 4 + j;
            if (rl < valid) {
                float* dst = out_h + (size_t)toks[rl] * D_DIM + gn0 + wn + lr;
                #pragma unroll
                for (int ni = 0; ni < 4; ++ni)
                    atomicAdd(dst + ni * 16, acc[mi][ni][j] + bb[ni]);
            }
        }
}

// MFMA tag head: relu(h) write-back + log_softmax(h @ W_tag + b_tag).
// 64 rows/block, 4 waves x 16 rows, acc 16x32 per wave.
__global__ __launch_bounds__(256) void k_tag(float* __restrict__ out_h,
                                             const float* __restrict__ Wt,
                                             const float* __restrict__ bt,
                                             float* __restrict__ out_tag) {
    __shared__ unsigned short Al[64 * 64];   // 8 KB
    __shared__ unsigned short Bl[32 * 64];   // 4 KB
    char* Alb = (char*)Al;
    char* Blb = (char*)Bl;
    int tok0 = blockIdx.x * 64;
    int t = threadIdx.x;
    int w = t >> 6, l = t & 63, lr = l & 15, lg = l >> 4;
    int wm = w * 16;
    int ar = t >> 4, ac = t & 15;
    int bn = t & 31, kh = t >> 5;
    f32x4 acc[2] = {};
    for (int k0 = 0; k0 < D_DIM; k0 += 64) {
        __syncthreads();
        #pragma unroll
        for (int s = 0; s < 4; ++s) {
            int row = s * 16 + ar;
            float* hp = out_h + (size_t)(tok0 + row) * D_DIM + k0 + ac * 4;
            float4 v = *(float4*)hp;
            v.x = fmaxf(v.x, 0.f); v.y = fmaxf(v.y, 0.f);
            v.z = fmaxf(v.z, 0.f); v.w = fmaxf(v.w, 0.f);
            *(float4*)hp = v;
            Pk4 u;
            u.s[0] = f2bf(v.x); u.s[1] = f2bf(v.y);
            u.s[2] = f2bf(v.z); u.s[3] = f2bf(v.w);
            *(uint2*)(Alb + row * 128 + ((ac * 8) ^ ((row & 7) << 4))) = u.d;
        }
        {
            Pk8 u;
            #pragma unroll
            for (int i = 0; i < 8; ++i)
                u.s[i] = f2bf(Wt[(size_t)(k0 + kh * 8 + i) * T_TAG + bn]);
            *(uint4*)(Blb + bn * 128 + ((kh * 16) ^ ((bn & 7) << 4))) = u.q;
        }
        __syncthreads();
        #pragma unroll
        for (int kk = 0; kk < 2; ++kk) {
            int koff = kk * 64 + lg * 16;
            bf16x8 af = *(const bf16x8*)(Alb + (wm + lr) * 128 +
                                         (koff ^ ((lr & 7) << 4)));
            #pragma unroll
            for (int ni = 0; ni < 2; ++ni) {
                bf16x8 bfr = *(const bf16x8*)(Blb + (ni * 16 + lr) * 128 +
                                              (koff ^ ((lr & 7) << 4)));
                acc[ni] = __builtin_amdgcn_mfma_f32_16x16x32_bf16(
                    af, bfr, acc[ni], 0, 0, 0);
            }
        }
    }
    float bt0 = bt[lr], bt1 = bt[16 + lr];
    #pragma unroll
    for (int j = 0; j < 4; ++j) {
        float v0 = acc[0][j] + bt0;
        float v1 = acc[1][j] + bt1;
        float m = fmaxf(v0, v1);
        #pragma unroll
        for (int s = 1; s < 16; s <<= 1) m = fmaxf(m, __shfl_xor(m, s));
        float sum = expf(v0 - m) + expf(v1 - m);
        #pragma unroll
        for (int s = 1; s < 16; s <<= 1) sum += __shfl_xor(sum, s);
        float lse = m + logf(sum);
        int row = tok0 + wm + lg * 4 + j;
        out_tag[(size_t)row * T_TAG + lr] = v0 - lse;
        out_tag[(size_t)row * T_TAG + 16 + lr] = v1 - lse;
    }
}

extern "C" void kernel_launch(void* const* d_in, const int* in_sizes, int n_in,
                              void* d_out, int out_size, void* d_ws, size_t ws_size,
                              hipStream_t stream) {
    const float* x     = (const float*)d_in[0];
    const float* Wself = (const float*)d_in[1];
    const float* bself = (const float*)d_in[2];
    const float* Wst   = (const float*)d_in[3];
    const float* Bst   = (const float*)d_in[4];
    const float* Wtag  = (const float*)d_in[5];
    const float* btag  = (const float*)d_in[6];
    const int*   etok  = (const int*)d_in[7];
    const int*   erel  = (const int*)d_in[8];
    float* out_tag = (float*)d_out;
    float* out_h   = (float*)d_out + (size_t)N_TOK * T_TAG;
    int* ws = (int*)d_ws;

    hipMemsetAsync(out_h, 0, (size_t)N_TOK * D_DIM * sizeof(float), stream);
    k_setup<<<1, 1024, 0, stream>>>(erel, ws);
    k_fused<<<dim3(GRID_ITEMS, D_DIM / 128), 256, 0, stream>>>(
        x, Wself, bself, Wst, Bst, etok, ws, out_h);
    k_tag<<<N_TOK / 64, 256, 0, stream>>>(out_h, Wtag, btag, out_tag);
}

// Round 6
// 158.175 us; speedup vs baseline: 7.6782x; 1.0463x over previous
//
#include <hip/hip_runtime.h>
#include <hip/hip_bf16.h>
#include <math.h>

#define N_TOK 4096
#define D_DIM 1024
#define R_REL 92
#define T_TAG 32
#define E_EDGE 8192
#define SELF_R 127
#define GRID_ITEMS 192   // 32 self chunks + up to 160 dep chunks

// ws int layout:
//   [0..127]        cnt_rel
//   [256..383]      off_rel (93 used)
//   [384]           n_items
//   [512..1023]     items (r<<16 | chunk); items[0..31] self (r=SELF_R)
//   [1024..9215]    token id per relation-sorted slot (8192)
//   [17408..21504]  tok_off (4097)
//   [22528..30719]  tok_list: relation-sorted positions p, grouped by token
// float scratch at ws+32768 ints:
//   rows [0..8191]      dep rows (position-indexed), bias included
//   rows [8192..12287]  self rows (token-indexed), bias included

typedef short bf16x8 __attribute__((ext_vector_type(8)));
typedef float f32x4 __attribute__((ext_vector_type(4)));

union Pk8 { uint4 q; unsigned short s[8]; };
union Pk4 { uint2 d; unsigned short s[4]; };

__device__ __forceinline__ unsigned short f2bf(float f) {
    union { __hip_bfloat16 b; unsigned short u; } c;
    c.b = __float2bfloat16(f);
    return c.u;
}

__global__ __launch_bounds__(1024) void k_setup(const int* __restrict__ rel,
                                                const int* __restrict__ tokv,
                                                int* __restrict__ ws) {
    __shared__ int cnt[128], offL[128], cur[128];
    __shared__ int sh[1024];
    __shared__ int tcnt[4096], toff[4096];
    int t = threadIdx.x;
    if (t < 128) { cnt[t] = 0; cur[t] = 0; }
    #pragma unroll
    for (int i = 0; i < 4; ++i) tcnt[i * 1024 + t] = 0;
    __syncthreads();
    int er[8], et[8];
    #pragma unroll
    for (int i = 0; i < 8; ++i) {
        er[i] = rel[i * 1024 + t];
        et[i] = tokv[i * 1024 + t];
        atomicAdd(&cnt[er[i]], 1);
        atomicAdd(&tcnt[et[i]], 1);
    }
    __syncthreads();
    // ---- scan relation counts (128) ----
    int c = (t < 128) ? cnt[t] : 0;
    int v = c;
    if (t < 128) sh[t] = v;
    __syncthreads();
    for (int st = 1; st < 128; st <<= 1) {
        int add = (t >= st && t < 128) ? sh[t - st] : 0;
        __syncthreads();
        if (t < 128) { v += add; sh[t] = v; }
        __syncthreads();
    }
    if (t < 128) { offL[t] = v - c; ws[256 + t] = v - c; ws[t] = c; }
    // ---- scan chunk counts -> items ----
    int ch = (t < R_REL) ? ((c + 127) >> 7) : 0;
    int v2 = ch;
    if (t < 128) sh[t] = v2;
    __syncthreads();
    for (int st = 1; st < 128; st <<= 1) {
        int add = (t >= st && t < 128) ? sh[t - st] : 0;
        __syncthreads();
        if (t < 128) { v2 += add; sh[t] = v2; }
        __syncthreads();
    }
    if (t < 32) ws[512 + t] = (SELF_R << 16) | t;
    if (t < R_REL) {
        int excl = v2 - ch;
        for (int j = 0; j < ch; ++j)
            ws[512 + 32 + excl + j] = (t << 16) | j;
    }
    if (t == 127) ws[384] = 32 + v2;
    // ---- scan token counts (4096, 4 per thread) ----
    int s0 = tcnt[4 * t + 0], s1 = tcnt[4 * t + 1];
    int s2 = tcnt[4 * t + 2], s3 = tcnt[4 * t + 3];
    int sum4 = s0 + s1 + s2 + s3;
    int vv = sum4;
    sh[t] = vv;
    __syncthreads();
    for (int st = 1; st < 1024; st <<= 1) {
        int add = (t >= st) ? sh[t - st] : 0;
        __syncthreads();
        vv += add; sh[t] = vv;
        __syncthreads();
    }
    int ex = vv - sum4;
    toff[4 * t + 0] = ex;
    toff[4 * t + 1] = ex + s0;
    toff[4 * t + 2] = ex + s0 + s1;
    toff[4 * t + 3] = ex + s0 + s1 + s2;
    ws[17408 + 4 * t + 0] = toff[4 * t + 0];
    ws[17408 + 4 * t + 1] = toff[4 * t + 1];
    ws[17408 + 4 * t + 2] = toff[4 * t + 2];
    ws[17408 + 4 * t + 3] = toff[4 * t + 3];
    if (t == 1023) ws[17408 + 4096] = vv;   // = E_EDGE
    __syncthreads();
    #pragma unroll
    for (int i = 0; i < 4; ++i) tcnt[i * 1024 + t] = 0;   // reuse as cursors
    __syncthreads();
    // ---- scatter: by relation (store token), and token-CSR (store position) ----
    #pragma unroll
    for (int i = 0; i < 8; ++i) {
        int pos = offL[er[i]] + atomicAdd(&cur[er[i]], 1);
        ws[1024 + pos] = et[i];
        int q = toff[et[i]] + atomicAdd(&tcnt[et[i]], 1);
        ws[22528 + q] = pos;
    }
}

// Fused grouped GEMM, T14 pipelined; writes rows densely to scratch (no atomics).
__global__ __launch_bounds__(256, 2) void k_fused(const float* __restrict__ x,
                                                  const float* __restrict__ Wself,
                                                  const float* __restrict__ bself,
                                                  const float* __restrict__ Wst,
                                                  const float* __restrict__ Bst,
                                                  const int* __restrict__ ws,
                                                  float* __restrict__ scratch) {
    if ((int)blockIdx.x >= ws[384]) return;
    int item = ws[512 + blockIdx.x];
    int r = item >> 16, chunk = item & 0xFFFF;
    int m0 = chunk * 128;
    int valid;
    const float* Wbase;
    const float* bias;
    bool is_self = (r == SELF_R);
    int off0 = 0;
    if (is_self) {
        valid = 128;
        Wbase = Wself;
        bias = bself;
    } else {
        int cnt = ws[r];
        off0 = ws[256 + r];
        valid = cnt - m0; if (valid > 128) valid = 128;
        Wbase = Wst + (size_t)r * D_DIM * D_DIM;
        bias = Bst + (size_t)r * D_DIM;
    }
    int srow_base = is_self ? (8192 + m0) : (off0 + m0);

    __shared__ unsigned short Al[128 * 64];
    __shared__ unsigned short Bl[128 * 64];
    __shared__ int toks[128];
    char* Alb = (char*)Al;
    char* Blb = (char*)Bl;
    int t = threadIdx.x;
    if (t < 128) {
        int tok;
        if (is_self) tok = m0 + t;
        else tok = (t < valid) ? ws[1024 + off0 + m0 + t] : 0;
        toks[t] = tok;
    }
    __syncthreads();

    int gn0 = blockIdx.y * 128;
    int w = t >> 6, l = t & 63;
    int lr = l & 15, lg = l >> 4;
    int wm = (w >> 1) * 64, wn = (w & 1) * 64;
    int ar = t >> 4, ac = t & 15;
    int tok_s[8];
    #pragma unroll
    for (int s = 0; s < 8; ++s) tok_s[s] = toks[s * 16 + ar];
    int bn = (w & 1) * 64 + l;
    int bkb = (w >> 1) * 32;
    const float* wcol = Wbase + gn0 + bn;

    float4 pa[8];
    float pb[32];

    #pragma unroll
    for (int s = 0; s < 8; ++s)
        pa[s] = *(const float4*)(x + (size_t)tok_s[s] * D_DIM + ac * 4);
    #pragma unroll
    for (int s = 0; s < 4; ++s)
        #pragma unroll
        for (int i = 0; i < 8; ++i)
            pb[s * 8 + i] = wcol[(size_t)(bkb + s * 8 + i) * D_DIM];
    #pragma unroll
    for (int s = 0; s < 8; ++s) {
        int row = s * 16 + ar;
        Pk4 u;
        u.s[0] = f2bf(pa[s].x); u.s[1] = f2bf(pa[s].y);
        u.s[2] = f2bf(pa[s].z); u.s[3] = f2bf(pa[s].w);
        *(uint2*)(Alb + row * 128 + ((ac * 8) ^ ((row & 7) << 4))) = u.d;
    }
    #pragma unroll
    for (int s = 0; s < 4; ++s) {
        Pk8 u;
        #pragma unroll
        for (int i = 0; i < 8; ++i) u.s[i] = f2bf(pb[s * 8 + i]);
        *(uint4*)(Blb + bn * 128 + ((bkb * 2 + s * 16) ^ ((bn & 7) << 4))) = u.q;
    }
    __syncthreads();

    f32x4 acc[4][4] = {};
    for (int k0 = 0; k0 < D_DIM; k0 += 64) {
        bool pf = (k0 + 64 < D_DIM);
        if (pf) {
            int kn = k0 + 64;
            #pragma unroll
            for (int s = 0; s < 8; ++s)
                pa[s] = *(const float4*)(x + (size_t)tok_s[s] * D_DIM + kn + ac * 4);
            #pragma unroll
            for (int s = 0; s < 4; ++s)
                #pragma unroll
                for (int i = 0; i < 8; ++i)
                    pb[s * 8 + i] = wcol[(size_t)(kn + bkb + s * 8 + i) * D_DIM];
        }
        #pragma unroll
        for (int kk = 0; kk < 2; ++kk) {
            int koff = kk * 64 + lg * 16;
            bf16x8 af[4], bfr[4];
            #pragma unroll
            for (int mi = 0; mi < 4; ++mi)
                af[mi] = *(const bf16x8*)(Alb + (wm + mi * 16 + lr) * 128 +
                                          (koff ^ ((lr & 7) << 4)));
            #pragma unroll
            for (int ni = 0; ni < 4; ++ni)
                bfr[ni] = *(const bf16x8*)(Blb + (wn + ni * 16 + lr) * 128 +
                                           (koff ^ ((lr & 7) << 4)));
            #pragma unroll
            for (int mi = 0; mi < 4; ++mi)
                #pragma unroll
                for (int ni = 0; ni < 4; ++ni)
                    acc[mi][ni] = __builtin_amdgcn_mfma_f32_16x16x32_bf16(
                        af[mi], bfr[ni], acc[mi][ni], 0, 0, 0);
        }
        __syncthreads();
        if (pf) {
            #pragma unroll
            for (int s = 0; s < 8; ++s) {
                int row = s * 16 + ar;
                Pk4 u;
                u.s[0] = f2bf(pa[s].x); u.s[1] = f2bf(pa[s].y);
                u.s[2] = f2bf(pa[s].z); u.s[3] = f2bf(pa[s].w);
                *(uint2*)(Alb + row * 128 + ((ac * 8) ^ ((row & 7) << 4))) = u.d;
            }
            #pragma unroll
            for (int s = 0; s < 4; ++s) {
                Pk8 u;
                #pragma unroll
                for (int i = 0; i < 8; ++i) u.s[i] = f2bf(pb[s * 8 + i]);
                *(uint4*)(Blb + bn * 128 + ((bkb * 2 + s * 16) ^ ((bn & 7) << 4))) = u.q;
            }
            __syncthreads();
        }
    }
    float bb[4];
    #pragma unroll
    for (int ni = 0; ni < 4; ++ni) bb[ni] = bias[gn0 + wn + ni * 16 + lr];
    #pragma unroll
    for (int mi = 0; mi < 4; ++mi)
        #pragma unroll
        for (int j = 0; j < 4; ++j) {
            int rl = wm + mi * 16 + lg * 4 + j;
            if (rl < valid) {
                float* dst = scratch + (size_t)(srow_base + rl) * D_DIM + gn0 + wn + lr;
                #pragma unroll
                for (int ni = 0; ni < 4; ++ni)
                    dst[ni * 16] = acc[mi][ni][j] + bb[ni];
            }
        }
}

// Per-token gather-reduce: h[tok] = relu(self_row + sum of dep rows)
__global__ __launch_bounds__(256) void k_reduce(const int* __restrict__ ws,
                                                const float* __restrict__ scratch,
                                                float* __restrict__ out_h) {
    int tok = blockIdx.x;
    int t = threadIdx.x;
    int j0 = ws[17408 + tok], j1 = ws[17408 + tok + 1];
    float4 a = *(const float4*)(scratch + (size_t)(8192 + tok) * D_DIM + t * 4);
    for (int j = j0; j < j1; ++j) {
        int p = ws[22528 + j];
        float4 d = *(const float4*)(scratch + (size_t)p * D_DIM + t * 4);
        a.x += d.x; a.y += d.y; a.z += d.z; a.w += d.w;
    }
    a.x = fmaxf(a.x, 0.f); a.y = fmaxf(a.y, 0.f);
    a.z = fmaxf(a.z, 0.f); a.w = fmaxf(a.w, 0.f);
    *(float4*)(out_h + (size_t)tok * D_DIM + t * 4) = a;
}

// MFMA tag head: tag = log_softmax(h @ W_tag + b_tag); h already relu'd.
__global__ __launch_bounds__(256) void k_tag(const float* __restrict__ out_h,
                                             const float* __restrict__ Wt,
                                             const float* __restrict__ bt,
                                             float* __restrict__ out_tag) {
    __shared__ unsigned short Al[64 * 64];
    __shared__ unsigned short Bl[32 * 64];
    char* Alb = (char*)Al;
    char* Blb = (char*)Bl;
    int tok0 = blockIdx.x * 64;
    int t = threadIdx.x;
    int w = t >> 6, l = t & 63, lr = l & 15, lg = l >> 4;
    int wm = w * 16;
    int ar = t >> 4, ac = t & 15;
    int bn = t & 31, kh = t >> 5;
    f32x4 acc[2] = {};
    for (int k0 = 0; k0 < D_DIM; k0 += 64) {
        __syncthreads();
        #pragma unroll
        for (int s = 0; s < 4; ++s) {
            int row = s * 16 + ar;
            const float* hp = out_h + (size_t)(tok0 + row) * D_DIM + k0 + ac * 4;
            float4 v = *(const float4*)hp;
            Pk4 u;
            u.s[0] = f2bf(v.x); u.s[1] = f2bf(v.y);
            u.s[2] = f2bf(v.z); u.s[3] = f2bf(v.w);
            *(uint2*)(Alb + row * 128 + ((ac * 8) ^ ((row & 7) << 4))) = u.d;
        }
        {
            Pk8 u;
            #pragma unroll
            for (int i = 0; i < 8; ++i)
                u.s[i] = f2bf(Wt[(size_t)(k0 + kh * 8 + i) * T_TAG + bn]);
            *(uint4*)(Blb + bn * 128 + ((kh * 16) ^ ((bn & 7) << 4))) = u.q;
        }
        __syncthreads();
        #pragma unroll
        for (int kk = 0; kk < 2; ++kk) {
            int koff = kk * 64 + lg * 16;
            bf16x8 af = *(const bf16x8*)(Alb + (wm + lr) * 128 +
                                         (koff ^ ((lr & 7) << 4)));
            #pragma unroll
            for (int ni = 0; ni < 2; ++ni) {
                bf16x8 bfr = *(const bf16x8*)(Blb + (ni * 16 + lr) * 128 +
                                              (koff ^ ((lr & 7) << 4)));
                acc[ni] = __builtin_amdgcn_mfma_f32_16x16x32_bf16(
                    af, bfr, acc[ni], 0, 0, 0);
            }
        }
    }
    float bt0 = bt[lr], bt1 = bt[16 + lr];
    #pragma unroll
    for (int j = 0; j < 4; ++j) {
        float v0 = acc[0][j] + bt0;
        float v1 = acc[1][j] + bt1;
        float m = fmaxf(v0, v1);
        #pragma unroll
        for (int s = 1; s < 16; s <<= 1) m = fmaxf(m, __shfl_xor(m, s));
        float sum = expf(v0 - m) + expf(v1 - m);
        #pragma unroll
        for (int s = 1; s < 16; s <<= 1) sum += __shfl_xor(sum, s);
        float lse = m + logf(sum);
        int row = tok0 + wm + lg * 4 + j;
        out_tag[(size_t)row * T_TAG + lr] = v0 - lse;
        out_tag[(size_t)row * T_TAG + 16 + lr] = v1 - lse;
    }
}

extern "C" void kernel_launch(void* const* d_in, const int* in_sizes, int n_in,
                              void* d_out, int out_size, void* d_ws, size_t ws_size,
                              hipStream_t stream) {
    const float* x     = (const float*)d_in[0];
    const float* Wself = (const float*)d_in[1];
    const float* bself = (const float*)d_in[2];
    const float* Wst   = (const float*)d_in[3];
    const float* Bst   = (const float*)d_in[4];
    const float* Wtag  = (const float*)d_in[5];
    const float* btag  = (const float*)d_in[6];
    const int*   etok  = (const int*)d_in[7];
    const int*   erel  = (const int*)d_in[8];
    float* out_tag = (float*)d_out;
    float* out_h   = (float*)d_out + (size_t)N_TOK * T_TAG;
    int* ws = (int*)d_ws;
    float* scratch = (float*)d_ws + 32768;

    k_setup<<<1, 1024, 0, stream>>>(erel, etok, ws);
    k_fused<<<dim3(GRID_ITEMS, D_DIM / 128), 256, 0, stream>>>(
        x, Wself, bself, Wst, Bst, ws, scratch);
    k_reduce<<<N_TOK, 256, 0, stream>>>(ws, scratch, out_h);
    k_tag<<<N_TOK / 64, 256, 0, stream>>>(out_h, Wtag, btag, out_tag);
}

// Round 7
// 149.431 us; speedup vs baseline: 8.1275x; 1.0585x over previous
//
#include <hip/hip_runtime.h>
#include <hip/hip_bf16.h>
#include <math.h>

#define N_TOK 4096
#define D_DIM 1024
#define R_REL 92
#define T_TAG 32
#define E_EDGE 8192
#define SELF_R 127
#define GRID_ITEMS 192   // 32 self chunks + up to 160 dep chunks

// ws int layout:
//   [0..127]        cnt_rel
//   [256..383]      off_rel (93 used)
//   [384]           n_items
//   [512..1023]     items (r<<16 | chunk); items[0..31] self (r=SELF_R)
//   [1024..9215]    token id per relation-sorted slot (8192)
//   [17408..21504]  tok_off (4097)
//   [22528..30719]  tok_list: relation-sorted positions, grouped by token
// bf16 scratch at ws+32768 ints:
//   rows [0..8191]     dep rows (position-indexed), bias included
//   rows [8192..12287] self rows (token-indexed), bias included

typedef short bf16x8 __attribute__((ext_vector_type(8)));
typedef float f32x4 __attribute__((ext_vector_type(4)));

union Pk8 { uint4 q; unsigned short s[8]; };
union Pk4 { uint2 d; unsigned short s[4]; };

__device__ __forceinline__ unsigned short f2bf(float f) {
    union { __hip_bfloat16 b; unsigned short u; } c;
    c.b = __float2bfloat16(f);
    return c.u;
}
__device__ __forceinline__ float bf2f(unsigned short u) {
    return __uint_as_float(((unsigned)u) << 16);
}

__global__ __launch_bounds__(1024) void k_setup(const int* __restrict__ rel,
                                                const int* __restrict__ tokv,
                                                int* __restrict__ ws) {
    __shared__ int cnt[128], offL[128], cur[128];
    __shared__ int sh[128];
    __shared__ int wsum[16];
    __shared__ int tcnt[4096], toff[4096];
    int t = threadIdx.x;
    int lane = t & 63, wid = t >> 6;
    if (t < 128) { cnt[t] = 0; cur[t] = 0; }
    #pragma unroll
    for (int i = 0; i < 4; ++i) tcnt[i * 1024 + t] = 0;
    __syncthreads();
    int er[8], et[8];
    #pragma unroll
    for (int i = 0; i < 8; ++i) {
        er[i] = rel[i * 1024 + t];
        et[i] = tokv[i * 1024 + t];
        atomicAdd(&cnt[er[i]], 1);
        atomicAdd(&tcnt[et[i]], 1);
    }
    __syncthreads();
    // ---- scan relation counts (128) ----
    int c = (t < 128) ? cnt[t] : 0;
    int v = c;
    if (t < 128) sh[t] = v;
    __syncthreads();
    for (int st = 1; st < 128; st <<= 1) {
        int add = (t >= st && t < 128) ? sh[t - st] : 0;
        __syncthreads();
        if (t < 128) { v += add; sh[t] = v; }
        __syncthreads();
    }
    if (t < 128) { offL[t] = v - c; ws[256 + t] = v - c; ws[t] = c; }
    // ---- scan chunk counts -> items ----
    int ch = (t < R_REL) ? ((c + 127) >> 7) : 0;
    int v2 = ch;
    if (t < 128) sh[t] = v2;
    __syncthreads();
    for (int st = 1; st < 128; st <<= 1) {
        int add = (t >= st && t < 128) ? sh[t - st] : 0;
        __syncthreads();
        if (t < 128) { v2 += add; sh[t] = v2; }
        __syncthreads();
    }
    if (t < 32) ws[512 + t] = (SELF_R << 16) | t;
    if (t < R_REL) {
        int excl = v2 - ch;
        for (int j = 0; j < ch; ++j)
            ws[512 + 32 + excl + j] = (t << 16) | j;
    }
    if (t == 127) ws[384] = 32 + v2;
    // ---- scan token counts (4096, 4/thread) via wave shfl scans ----
    int s0 = tcnt[4 * t + 0], s1 = tcnt[4 * t + 1];
    int s2 = tcnt[4 * t + 2], s3 = tcnt[4 * t + 3];
    int sum4 = s0 + s1 + s2 + s3;
    int vv = sum4;
    #pragma unroll
    for (int d = 1; d < 64; d <<= 1) {
        int n = __shfl_up(vv, d);
        if (lane >= d) vv += n;
    }
    if (lane == 63) wsum[wid] = vv;
    __syncthreads();
    if (wid == 0) {
        int wv = (lane < 16) ? wsum[lane] : 0;
        #pragma unroll
        for (int d = 1; d < 16; d <<= 1) {
            int n = __shfl_up(wv, d);
            if (lane >= d) wv += n;
        }
        if (lane < 16) wsum[lane] = wv;
    }
    __syncthreads();
    int base = (wid > 0) ? wsum[wid - 1] : 0;
    int incl = base + vv;
    int ex = incl - sum4;
    toff[4 * t + 0] = ex;
    toff[4 * t + 1] = ex + s0;
    toff[4 * t + 2] = ex + s0 + s1;
    toff[4 * t + 3] = ex + s0 + s1 + s2;
    ws[17408 + 4 * t + 0] = ex;
    ws[17408 + 4 * t + 1] = ex + s0;
    ws[17408 + 4 * t + 2] = ex + s0 + s1;
    ws[17408 + 4 * t + 3] = ex + s0 + s1 + s2;
    if (t == 1023) ws[17408 + 4096] = incl;   // = E_EDGE
    __syncthreads();
    #pragma unroll
    for (int i = 0; i < 4; ++i) tcnt[i * 1024 + t] = 0;   // reuse as cursors
    __syncthreads();
    #pragma unroll
    for (int i = 0; i < 8; ++i) {
        int pos = offL[er[i]] + atomicAdd(&cur[er[i]], 1);
        ws[1024 + pos] = et[i];
        int q = toff[et[i]] + atomicAdd(&tcnt[et[i]], 1);
        ws[22528 + q] = pos;
    }
}

// Fused grouped GEMM, double-buffered LDS, ONE barrier per K-step.
// Writes rows densely to bf16 scratch (plain stores).
__global__ __launch_bounds__(256, 2) void k_fused(const float* __restrict__ x,
                                                  const float* __restrict__ Wself,
                                                  const float* __restrict__ bself,
                                                  const float* __restrict__ Wst,
                                                  const float* __restrict__ Bst,
                                                  const int* __restrict__ ws,
                                                  unsigned short* __restrict__ scratch) {
    if ((int)blockIdx.x >= ws[384]) return;
    int item = ws[512 + blockIdx.x];
    int r = item >> 16, chunk = item & 0xFFFF;
    int m0 = chunk * 128;
    int valid;
    const float* Wbase;
    const float* bias;
    bool is_self = (r == SELF_R);
    int off0 = 0;
    if (is_self) {
        valid = 128;
        Wbase = Wself;
        bias = bself;
    } else {
        int cnt = ws[r];
        off0 = ws[256 + r];
        valid = cnt - m0; if (valid > 128) valid = 128;
        Wbase = Wst + (size_t)r * D_DIM * D_DIM;
        bias = Bst + (size_t)r * D_DIM;
    }
    int srow_base = is_self ? (8192 + m0) : (off0 + m0);

    __shared__ unsigned short Al[2][128 * 64];   // 16 KB x2
    __shared__ unsigned short Bl[2][128 * 64];   // 16 KB x2
    __shared__ int toks[128];
    int t = threadIdx.x;
    if (t < 128) {
        int tok;
        if (is_self) tok = m0 + t;
        else tok = (t < valid) ? ws[1024 + off0 + m0 + t] : 0;
        toks[t] = tok;
    }
    __syncthreads();

    int gn0 = blockIdx.y * 128;
    int w = t >> 6, l = t & 63;
    int lr = l & 15, lg = l >> 4;
    int wm = (w >> 1) * 64, wn = (w & 1) * 64;
    int ar = t >> 4, ac = t & 15;
    int tok_s[8];
    #pragma unroll
    for (int s = 0; s < 8; ++s) tok_s[s] = toks[s * 16 + ar];
    int bn = (w & 1) * 64 + l;
    int bkb = (w >> 1) * 32;
    const float* wcol = Wbase + gn0 + bn;

    float4 pa[8];
    float pb[32];

    // prologue: load + stage tile 0 into buf 0
    #pragma unroll
    for (int s = 0; s < 8; ++s)
        pa[s] = *(const float4*)(x + (size_t)tok_s[s] * D_DIM + ac * 4);
    #pragma unroll
    for (int s = 0; s < 4; ++s)
        #pragma unroll
        for (int i = 0; i < 8; ++i)
            pb[s * 8 + i] = wcol[(size_t)(bkb + s * 8 + i) * D_DIM];
    {
        char* Ab = (char*)Al[0];
        char* Bb = (char*)Bl[0];
        #pragma unroll
        for (int s = 0; s < 8; ++s) {
            int row = s * 16 + ar;
            Pk4 u;
            u.s[0] = f2bf(pa[s].x); u.s[1] = f2bf(pa[s].y);
            u.s[2] = f2bf(pa[s].z); u.s[3] = f2bf(pa[s].w);
            *(uint2*)(Ab + row * 128 + ((ac * 8) ^ ((row & 7) << 4))) = u.d;
        }
        #pragma unroll
        for (int s = 0; s < 4; ++s) {
            Pk8 u;
            #pragma unroll
            for (int i = 0; i < 8; ++i) u.s[i] = f2bf(pb[s * 8 + i]);
            *(uint4*)(Bb + bn * 128 + ((bkb * 2 + s * 16) ^ ((bn & 7) << 4))) = u.q;
        }
    }
    __syncthreads();

    f32x4 acc[4][4] = {};
    int cur = 0;
    for (int k0 = 0; k0 < D_DIM; k0 += 64) {
        bool pf = (k0 + 64 < D_DIM);
        if (pf) {                        // issue next-tile loads (fly over MFMA)
            int kn = k0 + 64;
            #pragma unroll
            for (int s = 0; s < 8; ++s)
                pa[s] = *(const float4*)(x + (size_t)tok_s[s] * D_DIM + kn + ac * 4);
            #pragma unroll
            for (int s = 0; s < 4; ++s)
                #pragma unroll
                for (int i = 0; i < 8; ++i)
                    pb[s * 8 + i] = wcol[(size_t)(kn + bkb + s * 8 + i) * D_DIM];
        }
        char* Ac = (char*)Al[cur];
        char* Bc = (char*)Bl[cur];
        #pragma unroll
        for (int kk = 0; kk < 2; ++kk) {
            int koff = kk * 64 + lg * 16;
            bf16x8 af[4], bfr[4];
            #pragma unroll
            for (int mi = 0; mi < 4; ++mi)
                af[mi] = *(const bf16x8*)(Ac + (wm + mi * 16 + lr) * 128 +
                                          (koff ^ ((lr & 7) << 4)));
            #pragma unroll
            for (int ni = 0; ni < 4; ++ni)
                bfr[ni] = *(const bf16x8*)(Bc + (wn + ni * 16 + lr) * 128 +
                                           (koff ^ ((lr & 7) << 4)));
            #pragma unroll
            for (int mi = 0; mi < 4; ++mi)
                #pragma unroll
                for (int ni = 0; ni < 4; ++ni)
                    acc[mi][ni] = __builtin_amdgcn_mfma_f32_16x16x32_bf16(
                        af[mi], bfr[ni], acc[mi][ni], 0, 0, 0);
        }
        if (pf) {                        // cvt+write tile t+1 into other buffer
            char* An = (char*)Al[cur ^ 1];
            char* Bn = (char*)Bl[cur ^ 1];
            #pragma unroll
            for (int s = 0; s < 8; ++s) {
                int row = s * 16 + ar;
                Pk4 u;
                u.s[0] = f2bf(pa[s].x); u.s[1] = f2bf(pa[s].y);
                u.s[2] = f2bf(pa[s].z); u.s[3] = f2bf(pa[s].w);
                *(uint2*)(An + row * 128 + ((ac * 8) ^ ((row & 7) << 4))) = u.d;
            }
            #pragma unroll
            for (int s = 0; s < 4; ++s) {
                Pk8 u;
                #pragma unroll
                for (int i = 0; i < 8; ++i) u.s[i] = f2bf(pb[s * 8 + i]);
                *(uint4*)(Bn + bn * 128 + ((bkb * 2 + s * 16) ^ ((bn & 7) << 4))) = u.q;
            }
        }
        __syncthreads();                 // single barrier per K-step
        cur ^= 1;
    }
    float bb[4];
    #pragma unroll
    for (int ni = 0; ni < 4; ++ni) bb[ni] = bias[gn0 + wn + ni * 16 + lr];
    #pragma unroll
    for (int mi = 0; mi < 4; ++mi)
        #pragma unroll
        for (int j = 0; j < 4; ++j) {
            int rl = wm + mi * 16 + lg * 4 + j;
            if (rl < valid) {
                unsigned short* dst = scratch +
                    (size_t)(srow_base + rl) * D_DIM + gn0 + wn + lr;
                #pragma unroll
                for (int ni = 0; ni < 4; ++ni)
                    dst[ni * 16] = f2bf(acc[mi][ni][j] + bb[ni]);
            }
        }
}

// Per-token gather-reduce: h[tok] = relu(self_row + sum of dep rows)
__global__ __launch_bounds__(256) void k_reduce(const int* __restrict__ ws,
                                                const unsigned short* __restrict__ scratch,
                                                float* __restrict__ out_h) {
    int tok = blockIdx.x;
    int t = threadIdx.x;
    int j0 = ws[17408 + tok], j1 = ws[17408 + tok + 1];
    ushort4 sv = *(const ushort4*)(scratch + (size_t)(8192 + tok) * D_DIM + t * 4);
    float a0 = bf2f(sv.x), a1 = bf2f(sv.y), a2 = bf2f(sv.z), a3 = bf2f(sv.w);
    for (int j = j0; j < j1; ++j) {
        int p = ws[22528 + j];
        ushort4 dv = *(const ushort4*)(scratch + (size_t)p * D_DIM + t * 4);
        a0 += bf2f(dv.x); a1 += bf2f(dv.y); a2 += bf2f(dv.z); a3 += bf2f(dv.w);
    }
    float4 o;
    o.x = fmaxf(a0, 0.f); o.y = fmaxf(a1, 0.f);
    o.z = fmaxf(a2, 0.f); o.w = fmaxf(a3, 0.f);
    *(float4*)(out_h + (size_t)tok * D_DIM + t * 4) = o;
}

// MFMA tag head: tag = log_softmax(h @ W_tag + b_tag); h already relu'd.
__global__ __launch_bounds__(256) void k_tag(const float* __restrict__ out_h,
                                             const float* __restrict__ Wt,
                                             const float* __restrict__ bt,
                                             float* __restrict__ out_tag) {
    __shared__ unsigned short Al[64 * 64];
    __shared__ unsigned short Bl[32 * 64];
    char* Alb = (char*)Al;
    char* Blb = (char*)Bl;
    int tok0 = blockIdx.x * 64;
    int t = threadIdx.x;
    int w = t >> 6, l = t & 63, lr = l & 15, lg = l >> 4;
    int wm = w * 16;
    int ar = t >> 4, ac = t & 15;
    int bn = t & 31, kh = t >> 5;
    f32x4 acc[2] = {};
    for (int k0 = 0; k0 < D_DIM; k0 += 64) {
        __syncthreads();
        #pragma unroll
        for (int s = 0; s < 4; ++s) {
            int row = s * 16 + ar;
            const float* hp = out_h + (size_t)(tok0 + row) * D_DIM + k0 + ac * 4;
            float4 v = *(const float4*)hp;
            Pk4 u;
            u.s[0] = f2bf(v.x); u.s[1] = f2bf(v.y);
            u.s[2] = f2bf(v.z); u.s[3] = f2bf(v.w);
            *(uint2*)(Alb + row * 128 + ((ac * 8) ^ ((row & 7) << 4))) = u.d;
        }
        {
            Pk8 u;
            #pragma unroll
            for (int i = 0; i < 8; ++i)
                u.s[i] = f2bf(Wt[(size_t)(k0 + kh * 8 + i) * T_TAG + bn]);
            *(uint4*)(Blb + bn * 128 + ((kh * 16) ^ ((bn & 7) << 4))) = u.q;
        }
        __syncthreads();
        #pragma unroll
        for (int kk = 0; kk < 2; ++kk) {
            int koff = kk * 64 + lg * 16;
            bf16x8 af = *(const bf16x8*)(Alb + (wm + lr) * 128 +
                                         (koff ^ ((lr & 7) << 4)));
            #pragma unroll
            for (int ni = 0; ni < 2; ++ni) {
                bf16x8 bfr = *(const bf16x8*)(Blb + (ni * 16 + lr) * 128 +
                                              (koff ^ ((lr & 7) << 4)));
                acc[ni] = __builtin_amdgcn_mfma_f32_16x16x32_bf16(
                    af, bfr, acc[ni], 0, 0, 0);
            }
        }
    }
    float bt0 = bt[lr], bt1 = bt[16 + lr];
    #pragma unroll
    for (int j = 0; j < 4; ++j) {
        float v0 = acc[0][j] + bt0;
        float v1 = acc[1][j] + bt1;
        float m = fmaxf(v0, v1);
        #pragma unroll
        for (int s = 1; s < 16; s <<= 1) m = fmaxf(m, __shfl_xor(m, s));
        float sum = expf(v0 - m) + expf(v1 - m);
        #pragma unroll
        for (int s = 1; s < 16; s <<= 1) sum += __shfl_xor(sum, s);
        float lse = m + logf(sum);
        int row = tok0 + wm + lg * 4 + j;
        out_tag[(size_t)row * T_TAG + lr] = v0 - lse;
        out_tag[(size_t)row * T_TAG + 16 + lr] = v1 - lse;
    }
}

extern "C" void kernel_launch(void* const* d_in, const int* in_sizes, int n_in,
                              void* d_out, int out_size, void* d_ws, size_t ws_size,
                              hipStream_t stream) {
    const float* x     = (const float*)d_in[0];
    const float* Wself = (const float*)d_in[1];
    const float* bself = (const float*)d_in[2];
    const float* Wst   = (const float*)d_in[3];
    const float* Bst   = (const float*)d_in[4];
    const float* Wtag  = (const float*)d_in[5];
    const float* btag  = (const float*)d_in[6];
    const int*   etok  = (const int*)d_in[7];
    const int*   erel  = (const int*)d_in[8];
    float* out_tag = (float*)d_out;
    float* out_h   = (float*)d_out + (size_t)N_TOK * T_TAG;
    int* ws = (int*)d_ws;
    unsigned short* scratch = (unsigned short*)((int*)d_ws + 32768);

    k_setup<<<1, 1024, 0, stream>>>(erel, etok, ws);
    k_fused<<<dim3(GRID_ITEMS, D_DIM / 128), 256, 0, stream>>>(
        x, Wself, bself, Wst, Bst, ws, scratch);
    k_reduce<<<N_TOK, 256, 0, stream>>>(ws, scratch, out_h);
    k_tag<<<N_TOK / 64, 256, 0, stream>>>(out_h, Wtag, btag, out_tag);
}

// Round 8
// 144.606 us; speedup vs baseline: 8.3987x; 1.0334x over previous
//
#include <hip/hip_runtime.h>
#include <hip/hip_bf16.h>
#include <math.h>

#define N_TOK 4096
#define D_DIM 1024
#define R_REL 92
#define T_TAG 32
#define E_EDGE 8192
#define SELF_R 127
#define GRID_ITEMS 192   // 32 self chunks + up to 160 dep chunks

// ws int layout:
//   [0..127]        cnt_rel
//   [256..383]      off_rel (93 used)
//   [384]           n_items
//   [512..1023]     items (r<<16 | chunk); items[0..31] self (r=SELF_R)
//   [1024..9215]    token id per relation-sorted slot (8192)
//   [17408..21504]  tok_off (4097)
//   [22528..30719]  tok_list: relation-sorted positions, grouped by token
// bf16 scratch at ws+32768 ints: rows [0..8191] dep, [8192..12287] self
// bf16 xb (x pre-converted) after scratch: 4096x1024

typedef short bf16x8 __attribute__((ext_vector_type(8)));
typedef float f32x4 __attribute__((ext_vector_type(4)));

union Pk8 { uint4 q; unsigned short s[8]; };
union Pk4 { uint2 d; unsigned short s[4]; };

__device__ __forceinline__ unsigned short f2bf(float f) {
    union { __hip_bfloat16 b; unsigned short u; } c;
    c.b = __float2bfloat16(f);
    return c.u;
}
__device__ __forceinline__ float bf2f(unsigned short u) {
    return __uint_as_float(((unsigned)u) << 16);
}
__device__ __forceinline__ void gload_lds16(const void* g, void* l) {
    __builtin_amdgcn_global_load_lds(
        (const __attribute__((address_space(1))) unsigned int*)g,
        (__attribute__((address_space(3))) unsigned int*)l, 16, 0, 0);
}

// block 0: edge setup; blocks 1..512: x -> bf16 convert
__global__ __launch_bounds__(1024) void k_prep(const int* __restrict__ rel,
                                               const int* __restrict__ tokv,
                                               const float* __restrict__ x,
                                               int* __restrict__ ws,
                                               unsigned short* __restrict__ xb) {
    int t = threadIdx.x;
    if (blockIdx.x > 0) {
        size_t base = ((size_t)(blockIdx.x - 1) * 1024 + t) * 8;
        float4 v0 = *(const float4*)(x + base);
        float4 v1 = *(const float4*)(x + base + 4);
        Pk8 u;
        u.s[0] = f2bf(v0.x); u.s[1] = f2bf(v0.y);
        u.s[2] = f2bf(v0.z); u.s[3] = f2bf(v0.w);
        u.s[4] = f2bf(v1.x); u.s[5] = f2bf(v1.y);
        u.s[6] = f2bf(v1.z); u.s[7] = f2bf(v1.w);
        *(uint4*)(xb + base) = u.q;
        return;
    }
    __shared__ int cnt[128], offL[128], cur[128];
    __shared__ int sh[128];
    __shared__ int wsum[16];
    __shared__ int tcnt[4096], toff[4096];
    int lane = t & 63, wid = t >> 6;
    if (t < 128) { cnt[t] = 0; cur[t] = 0; }
    #pragma unroll
    for (int i = 0; i < 4; ++i) tcnt[i * 1024 + t] = 0;
    __syncthreads();
    int er[8], et[8];
    #pragma unroll
    for (int i = 0; i < 8; ++i) {
        er[i] = rel[i * 1024 + t];
        et[i] = tokv[i * 1024 + t];
        atomicAdd(&cnt[er[i]], 1);
        atomicAdd(&tcnt[et[i]], 1);
    }
    __syncthreads();
    int c = (t < 128) ? cnt[t] : 0;
    int v = c;
    if (t < 128) sh[t] = v;
    __syncthreads();
    for (int st = 1; st < 128; st <<= 1) {
        int add = (t >= st && t < 128) ? sh[t - st] : 0;
        __syncthreads();
        if (t < 128) { v += add; sh[t] = v; }
        __syncthreads();
    }
    if (t < 128) { offL[t] = v - c; ws[256 + t] = v - c; ws[t] = c; }
    int ch = (t < R_REL) ? ((c + 127) >> 7) : 0;
    int v2 = ch;
    if (t < 128) sh[t] = v2;
    __syncthreads();
    for (int st = 1; st < 128; st <<= 1) {
        int add = (t >= st && t < 128) ? sh[t - st] : 0;
        __syncthreads();
        if (t < 128) { v2 += add; sh[t] = v2; }
        __syncthreads();
    }
    if (t < 32) ws[512 + t] = (SELF_R << 16) | t;
    if (t < R_REL) {
        int excl = v2 - ch;
        for (int j = 0; j < ch; ++j)
            ws[512 + 32 + excl + j] = (t << 16) | j;
    }
    if (t == 127) ws[384] = 32 + v2;
    // token-count scan via wave shfl scans
    int s0 = tcnt[4 * t + 0], s1 = tcnt[4 * t + 1];
    int s2 = tcnt[4 * t + 2], s3 = tcnt[4 * t + 3];
    int sum4 = s0 + s1 + s2 + s3;
    int vv = sum4;
    #pragma unroll
    for (int d = 1; d < 64; d <<= 1) {
        int n = __shfl_up(vv, d);
        if (lane >= d) vv += n;
    }
    if (lane == 63) wsum[wid] = vv;
    __syncthreads();
    if (wid == 0) {
        int wv = (lane < 16) ? wsum[lane] : 0;
        #pragma unroll
        for (int d = 1; d < 16; d <<= 1) {
            int n = __shfl_up(wv, d);
            if (lane >= d) wv += n;
        }
        if (lane < 16) wsum[lane] = wv;
    }
    __syncthreads();
    int base = (wid > 0) ? wsum[wid - 1] : 0;
    int incl = base + vv;
    int ex = incl - sum4;
    toff[4 * t + 0] = ex;
    toff[4 * t + 1] = ex + s0;
    toff[4 * t + 2] = ex + s0 + s1;
    toff[4 * t + 3] = ex + s0 + s1 + s2;
    ws[17408 + 4 * t + 0] = ex;
    ws[17408 + 4 * t + 1] = ex + s0;
    ws[17408 + 4 * t + 2] = ex + s0 + s1;
    ws[17408 + 4 * t + 3] = ex + s0 + s1 + s2;
    if (t == 1023) ws[17408 + 4096] = incl;
    __syncthreads();
    #pragma unroll
    for (int i = 0; i < 4; ++i) tcnt[i * 1024 + t] = 0;
    __syncthreads();
    #pragma unroll
    for (int i = 0; i < 8; ++i) {
        int pos = offL[er[i]] + atomicAdd(&cur[er[i]], 1);
        ws[1024 + pos] = et[i];
        int q = toff[et[i]] + atomicAdd(&tcnt[et[i]], 1);
        ws[22528 + q] = pos;
    }
}

// Fused grouped GEMM: 128x128xBK=64, 8 waves (2x4 of 64x32), dbuf LDS,
// A staged via global_load_lds from bf16 xb (swizzle folded into source addr),
// B reg-staged f32->bf16. One barrier per K-step. Dense bf16 scratch output.
__global__ __launch_bounds__(512, 4) void k_fused(const float* __restrict__ Wself,
                                                  const float* __restrict__ bself,
                                                  const float* __restrict__ Wst,
                                                  const float* __restrict__ Bst,
                                                  const int* __restrict__ ws,
                                                  const unsigned short* __restrict__ xb,
                                                  unsigned short* __restrict__ scratch) {
    if ((int)blockIdx.x >= ws[384]) return;
    int item = ws[512 + blockIdx.x];
    int r = item >> 16, chunk = item & 0xFFFF;
    int m0 = chunk * 128;
    int valid;
    const float* Wbase;
    const float* bias;
    bool is_self = (r == SELF_R);
    int off0 = 0;
    if (is_self) {
        valid = 128;
        Wbase = Wself;
        bias = bself;
    } else {
        int cnt = ws[r];
        off0 = ws[256 + r];
        valid = cnt - m0; if (valid > 128) valid = 128;
        Wbase = Wst + (size_t)r * D_DIM * D_DIM;
        bias = Bst + (size_t)r * D_DIM;
    }
    int srow_base = is_self ? (8192 + m0) : (off0 + m0);

    __shared__ unsigned short Al[2][8192];   // [row][k] bf16, XOR-swizzled, 16 KB x2
    __shared__ unsigned short Bl[2][8192];   // [n][k]   bf16, XOR-swizzled, 16 KB x2
    __shared__ int toks[128];
    int t = threadIdx.x;
    if (t < 128) {
        int tok;
        if (is_self) tok = m0 + t;
        else tok = (t < valid) ? ws[1024 + off0 + m0 + t] : 0;
        toks[t] = tok;
    }
    __syncthreads();

    int gn0 = blockIdx.y * 128;
    int wid = t >> 6, l = t & 63;
    int lr = l & 15, lg = l >> 4;
    int wm = (wid >> 2) * 64, wn = (wid & 3) * 32;

    // A staging: wave wid stages rows [wid*16, wid*16+16) as two 1-KB chunks.
    // Per-lane global source carries the XOR swizzle; LDS dest is linear.
    int row0 = wid * 16 + (l >> 3);
    int row1 = row0 + 8;
    const char* ga0 = (const char*)(xb + (size_t)toks[row0] * D_DIM) +
                      (((l & 7) * 16) ^ ((row0 & 7) << 4));
    const char* ga1 = (const char*)(xb + (size_t)toks[row1] * D_DIM) +
                      (((l & 7) * 16) ^ ((row1 & 7) << 4));

    // B staging: thread covers column bcol, k-quarter bkq (16 k's)
    int bcol = t & 127, bkq = t >> 7;
    const float* wp = Wbase + (size_t)bkq * 16 * D_DIM + gn0 + bcol;
    int bswz = (bcol & 7) << 4;
    int bb0 = bcol * 128 + ((bkq * 32) ^ bswz);
    int bb1 = bcol * 128 + ((bkq * 32 + 16) ^ bswz);

    float pb[16];
    // ---- prologue: stage tile 0 into buf 0 ----
    gload_lds16(ga0, (char*)Al[0] + wid * 2048);
    gload_lds16(ga1, (char*)Al[0] + wid * 2048 + 1024);
    ga0 += 128; ga1 += 128;
    #pragma unroll
    for (int i = 0; i < 16; ++i) pb[i] = wp[(size_t)i * D_DIM];
    {
        Pk8 u0, u1;
        #pragma unroll
        for (int i = 0; i < 8; ++i) { u0.s[i] = f2bf(pb[i]); u1.s[i] = f2bf(pb[8 + i]); }
        *(uint4*)((char*)Bl[0] + bb0) = u0.q;
        *(uint4*)((char*)Bl[0] + bb1) = u1.q;
    }
    __syncthreads();

    f32x4 acc[4][2] = {};
    int cur = 0;
    for (int k0 = 0; k0 < D_DIM; k0 += 64) {
        bool pf = (k0 + 64 < D_DIM);
        int nxt = cur ^ 1;
        if (pf) {                        // issue next-tile loads; fly over MFMA
            gload_lds16(ga0, (char*)Al[nxt] + wid * 2048);
            gload_lds16(ga1, (char*)Al[nxt] + wid * 2048 + 1024);
            ga0 += 128; ga1 += 128;
            #pragma unroll
            for (int i = 0; i < 16; ++i)
                pb[i] = wp[(size_t)(k0 + 64 + i) * D_DIM];
        }
        const char* Ac = (const char*)Al[cur];
        const char* Bc = (const char*)Bl[cur];
        #pragma unroll
        for (int kk = 0; kk < 2; ++kk) {
            int koff = kk * 64 + lg * 16;
            int sw = (lr & 7) << 4;
            bf16x8 af[4], bfr[2];
            #pragma unroll
            for (int mi = 0; mi < 4; ++mi)
                af[mi] = *(const bf16x8*)(Ac + (wm + mi * 16 + lr) * 128 + (koff ^ sw));
            #pragma unroll
            for (int ni = 0; ni < 2; ++ni)
                bfr[ni] = *(const bf16x8*)(Bc + (wn + ni * 16 + lr) * 128 + (koff ^ sw));
            #pragma unroll
            for (int mi = 0; mi < 4; ++mi)
                #pragma unroll
                for (int ni = 0; ni < 2; ++ni)
                    acc[mi][ni] = __builtin_amdgcn_mfma_f32_16x16x32_bf16(
                        af[mi], bfr[ni], acc[mi][ni], 0, 0, 0);
        }
        if (pf) {                        // cvt+write B(t+1) into other buffer
            Pk8 u0, u1;
            #pragma unroll
            for (int i = 0; i < 8; ++i) { u0.s[i] = f2bf(pb[i]); u1.s[i] = f2bf(pb[8 + i]); }
            *(uint4*)((char*)Bl[nxt] + bb0) = u0.q;
            *(uint4*)((char*)Bl[nxt] + bb1) = u1.q;
        }
        __syncthreads();                 // one barrier per K-step
        cur = nxt;
    }
    float bb[2];
    bb[0] = bias[gn0 + wn + lr];
    bb[1] = bias[gn0 + wn + 16 + lr];
    #pragma unroll
    for (int mi = 0; mi < 4; ++mi)
        #pragma unroll
        for (int j = 0; j < 4; ++j) {
            int rl = wm + mi * 16 + lg * 4 + j;
            if (rl < valid) {
                unsigned short* dst = scratch +
                    (size_t)(srow_base + rl) * D_DIM + gn0 + wn + lr;
                dst[0]  = f2bf(acc[mi][0][j] + bb[0]);
                dst[16] = f2bf(acc[mi][1][j] + bb[1]);
            }
        }
}

// Per-token gather-reduce: h[tok] = relu(self_row + sum of dep rows)
__global__ __launch_bounds__(256) void k_reduce(const int* __restrict__ ws,
                                                const unsigned short* __restrict__ scratch,
                                                float* __restrict__ out_h) {
    int tok = blockIdx.x;
    int t = threadIdx.x;
    int j0 = ws[17408 + tok], j1 = ws[17408 + tok + 1];
    ushort4 sv = *(const ushort4*)(scratch + (size_t)(8192 + tok) * D_DIM + t * 4);
    float a0 = bf2f(sv.x), a1 = bf2f(sv.y), a2 = bf2f(sv.z), a3 = bf2f(sv.w);
    for (int j = j0; j < j1; ++j) {
        int p = ws[22528 + j];
        ushort4 dv = *(const ushort4*)(scratch + (size_t)p * D_DIM + t * 4);
        a0 += bf2f(dv.x); a1 += bf2f(dv.y); a2 += bf2f(dv.z); a3 += bf2f(dv.w);
    }
    float4 o;
    o.x = fmaxf(a0, 0.f); o.y = fmaxf(a1, 0.f);
    o.z = fmaxf(a2, 0.f); o.w = fmaxf(a3, 0.f);
    *(float4*)(out_h + (size_t)tok * D_DIM + t * 4) = o;
}

// MFMA tag head: tag = log_softmax(h @ W_tag + b_tag); h already relu'd.
__global__ __launch_bounds__(256) void k_tag(const float* __restrict__ out_h,
                                             const float* __restrict__ Wt,
                                             const float* __restrict__ bt,
                                             float* __restrict__ out_tag) {
    __shared__ unsigned short Al[64 * 64];
    __shared__ unsigned short Bl[32 * 64];
    char* Alb = (char*)Al;
    char* Blb = (char*)Bl;
    int tok0 = blockIdx.x * 64;
    int t = threadIdx.x;
    int w = t >> 6, l = t & 63, lr = l & 15, lg = l >> 4;
    int wm = w * 16;
    int ar = t >> 4, ac = t & 15;
    int bn = t & 31, kh = t >> 5;
    f32x4 acc[2] = {};
    for (int k0 = 0; k0 < D_DIM; k0 += 64) {
        __syncthreads();
        #pragma unroll
        for (int s = 0; s < 4; ++s) {
            int row = s * 16 + ar;
            const float* hp = out_h + (size_t)(tok0 + row) * D_DIM + k0 + ac * 4;
            float4 v = *(const float4*)hp;
            Pk4 u;
            u.s[0] = f2bf(v.x); u.s[1] = f2bf(v.y);
            u.s[2] = f2bf(v.z); u.s[3] = f2bf(v.w);
            *(uint2*)(Alb + row * 128 + ((ac * 8) ^ ((row & 7) << 4))) = u.d;
        }
        {
            Pk8 u;
            #pragma unroll
            for (int i = 0; i < 8; ++i)
                u.s[i] = f2bf(Wt[(size_t)(k0 + kh * 8 + i) * T_TAG + bn]);
            *(uint4*)(Blb + bn * 128 + ((kh * 16) ^ ((bn & 7) << 4))) = u.q;
        }
        __syncthreads();
        #pragma unroll
        for (int kk = 0; kk < 2; ++kk) {
            int koff = kk * 64 + lg * 16;
            bf16x8 af = *(const bf16x8*)(Alb + (wm + lr) * 128 +
                                         (koff ^ ((lr & 7) << 4)));
            #pragma unroll
            for (int ni = 0; ni < 2; ++ni) {
                bf16x8 bfr = *(const bf16x8*)(Blb + (ni * 16 + lr) * 128 +
                                              (koff ^ ((lr & 7) << 4)));
                acc[ni] = __builtin_amdgcn_mfma_f32_16x16x32_bf16(
                    af, bfr, acc[ni], 0, 0, 0);
            }
        }
    }
    float bt0 = bt[lr], bt1 = bt[16 + lr];
    #pragma unroll
    for (int j = 0; j < 4; ++j) {
        float v0 = acc[0][j] + bt0;
        float v1 = acc[1][j] + bt1;
        float m = fmaxf(v0, v1);
        #pragma unroll
        for (int s = 1; s < 16; s <<= 1) m = fmaxf(m, __shfl_xor(m, s));
        float sum = expf(v0 - m) + expf(v1 - m);
        #pragma unroll
        for (int s = 1; s < 16; s <<= 1) sum += __shfl_xor(sum, s);
        float lse = m + logf(sum);
        int row = tok0 + wm + lg * 4 + j;
        out_tag[(size_t)row * T_TAG + lr] = v0 - lse;
        out_tag[(size_t)row * T_TAG + 16 + lr] = v1 - lse;
    }
}

extern "C" void kernel_launch(void* const* d_in, const int* in_sizes, int n_in,
                              void* d_out, int out_size, void* d_ws, size_t ws_size,
                              hipStream_t stream) {
    const float* x     = (const float*)d_in[0];
    const float* Wself = (const float*)d_in[1];
    const float* bself = (const float*)d_in[2];
    const float* Wst   = (const float*)d_in[3];
    const float* Bst   = (const float*)d_in[4];
    const float* Wtag  = (const float*)d_in[5];
    const float* btag  = (const float*)d_in[6];
    const int*   etok  = (const int*)d_in[7];
    const int*   erel  = (const int*)d_in[8];
    float* out_tag = (float*)d_out;
    float* out_h   = (float*)d_out + (size_t)N_TOK * T_TAG;
    int* ws = (int*)d_ws;
    unsigned short* scratch = (unsigned short*)((int*)d_ws + 32768);
    unsigned short* xb = scratch + (size_t)12288 * 1024;

    k_prep<<<513, 1024, 0, stream>>>(erel, etok, x, ws, xb);
    k_fused<<<dim3(GRID_ITEMS, D_DIM / 128), 512, 0, stream>>>(
        Wself, bself, Wst, Bst, ws, xb, scratch);
    k_reduce<<<N_TOK, 256, 0, stream>>>(ws, scratch, out_h);
    k_tag<<<N_TOK / 64, 256, 0, stream>>>(out_h, Wtag, btag, out_tag);
}